// Round 2
// baseline (11702.195 us; speedup 1.0000x reference)
//
#include <hip/hip_runtime.h>
#include <math.h>

#define HDIM 1024
#define BROWS 256
#define TSTEPS 64
#define TH3 3072
#define RSCALE 1024.0f
#define RINV   0.0009765625f   // 2^-10

typedef _Float16 half8 __attribute__((ext_vector_type(8)));
typedef float float4v __attribute__((ext_vector_type(4)));

__device__ __forceinline__ float sigmoidf_(float x) {
    return 1.0f / (1.0f + __expf(-x));
}

__device__ __forceinline__ float4v mfma16(half8 a, half8 b, float4v c) {
    return __builtin_amdgcn_mfma_f32_16x16x32_f16(a, b, c, 0, 0, 0);
}

// halfword index of element (m,k) in a [256][1024] plane stored in MFMA
// A-fragment order: [mtile][ktile][lane][slot], lane=(m&15)+16*((k&31)>>3),
// slot=k&7. A wave's (mtile,ktile) fragment is 1KB contiguous.
__device__ __forceinline__ int frag_idx(int m, int k) {
    return (((m >> 4) * 32 + (k >> 5)) * 64 + ((m & 15) + (((k & 31) >> 3) << 4))) * 8 + (k & 7);
}

__device__ __forceinline__ void split16(float v, _Float16* hp, _Float16* lp) {
    const _Float16 h = (_Float16)v;
    *hp = h;
    *lp = (_Float16)((v - (float)h) * RSCALE);
}

// Write-through 2-byte store: sc0 sc1 -> bypasses L1/L2 to the device
// coherence point. L2 never holds dirty shared lines, so the grid barrier
// needs no writeback walk.
__device__ __forceinline__ void st_h16(_Float16* p, _Float16 v) {
    const unsigned u = (unsigned)__builtin_bit_cast(unsigned short, v);
    asm volatile("global_store_short %0, %1, off sc0 sc1"
                 :: "v"(p), "v"(u) : "memory");
}

// ---------------------------------------------------------------------------
// Split grid barrier (256 blocks = 8 groups x 32).
// arrive: vmcnt(0) drains SHARED stores, block barrier, relaxed atomic add.
// (private stores, e.g. dout, can be issued between arrive and wait -> their
//  latency hides under the spin)
// wait: thread-0 spin on root counter, block barrier, inv-only acquire fence.
// ---------------------------------------------------------------------------
__device__ __forceinline__ void gbar_arrive(unsigned* bar, unsigned gen) {
    asm volatile("s_waitcnt vmcnt(0)" ::: "memory");
    __syncthreads();
    if (threadIdx.x == 0) {
        unsigned* gc = bar + ((blockIdx.x & 7) << 5);   // 128B-separated group counters
        unsigned* rc = bar + 256;                       // root counter (own line)
        const unsigned old = __hip_atomic_fetch_add(gc, 1u, __ATOMIC_RELAXED,
                                                    __HIP_MEMORY_SCOPE_AGENT);
        if (old + 1u == gen * 32u)
            __hip_atomic_fetch_add(rc, 1u, __ATOMIC_RELAXED,
                                   __HIP_MEMORY_SCOPE_AGENT);
    }
}

__device__ __forceinline__ void gbar_wait(unsigned* bar, unsigned gen) {
    if (threadIdx.x == 0) {
        unsigned* rc = bar + 256;
        while (__hip_atomic_load(rc, __ATOMIC_RELAXED,
                                 __HIP_MEMORY_SCOPE_AGENT) < gen * 8u)
            __builtin_amdgcn_s_sleep(1);
    }
    __syncthreads();
    __builtin_amdgcn_fence(__ATOMIC_ACQUIRE, "agent");
}

__device__ __forceinline__ void gbar(unsigned* bar, unsigned gen) {
    gbar_arrive(bar, gen);
    gbar_wait(bar, gen);
}

// ---------------------------------------------------------------------------
// 3-pass split-fp16 GEMM panel with explicit register double-buffering.
// Chunk = 4 k-tiles (16 global lane-loads of 16B issued ahead) -> sustained
// ~16-32 outstanding loads/wave instead of the compiler's ~3 (latency was
// the round-1 bottleneck: 1MB/CU/phase at only 28 GB/s effective).
// All rA indices are compile-time (full unroll) so the array stays in VGPRs.
// ---------------------------------------------------------------------------
__device__ __forceinline__ void gemm_panel(
    const half8* __restrict__ AH, const half8* __restrict__ AL,
    const _Float16* __restrict__ WH, const _Float16* __restrict__ WL,
    int mt0, int mt1, int lane,
    float4v& aH0, float4v& aXa0, float4v& aXb0,
    float4v& aH1, float4v& aXa1, float4v& aXb1)
{
    half8 rA[2][4][4];
    const int base0 = mt0 * 32 * 64 + lane;
    const int base1 = mt1 * 32 * 64 + lane;
    const int lofs = lane * 8;
#pragma unroll
    for (int kk = 0; kk < 4; ++kk) {
        rA[0][kk][0] = AH[base0 + kk * 64];
        rA[0][kk][1] = AL[base0 + kk * 64];
        rA[0][kk][2] = AH[base1 + kk * 64];
        rA[0][kk][3] = AL[base1 + kk * 64];
    }
#pragma unroll
    for (int c = 0; c < 8; ++c) {
        if (c < 7) {
#pragma unroll
            for (int kk = 0; kk < 4; ++kk) {
                const int kt = (c + 1) * 4 + kk;
                rA[(c + 1) & 1][kk][0] = AH[base0 + kt * 64];
                rA[(c + 1) & 1][kk][1] = AL[base0 + kt * 64];
                rA[(c + 1) & 1][kk][2] = AH[base1 + kt * 64];
                rA[(c + 1) & 1][kk][3] = AL[base1 + kt * 64];
            }
        }
#pragma unroll
        for (int kk = 0; kk < 4; ++kk) {
            const int kt = c * 4 + kk;
            const half8 bh = *(const half8*)&WH[kt * 512 + lofs];
            const half8 bl = *(const half8*)&WL[kt * 512 + lofs];
            const half8 a0h = rA[c & 1][kk][0];
            const half8 a0l = rA[c & 1][kk][1];
            const half8 a1h = rA[c & 1][kk][2];
            const half8 a1l = rA[c & 1][kk][3];
            aH0  = mfma16(a0h, bh, aH0);
            aXa0 = mfma16(a0l, bh, aXa0);
            aXb0 = mfma16(a0h, bl, aXb0);
            aH1  = mfma16(a1h, bh, aH1);
            aXa1 = mfma16(a1l, bh, aXa1);
            aXb1 = mfma16(a1h, bl, aXb1);
        }
    }
}

// ===========================================================================
// Persistent cooperative kernel: 256 blocks x 512 threads (8 waves, 2/SIMD).
// LDS 140KB: WAh/WAl = phase-A panel [4 cols W_out | 12 W_r gate cols of
//            THIS block] as split-fp16 B-fragments;
//            WBh/WBl = 12 interleaved gate cols of W_k; mhs = [256][12] fp32.
// Activations in global as split-fp16 A-fragment planes (hH/hL, oH/oL),
// written through (sc0 sc1); mh never leaves the block (LDS); h state kept
// in registers by the gate lanes. Split grid barrier; register-pipelined
// k-loops for memory-level parallelism.
// ===========================================================================
__global__ __launch_bounds__(512, 2) void decoder_mfma(
    const float* __restrict__ x,
    const float* __restrict__ W_fs, const float* __restrict__ b_fs,
    const float* __restrict__ W_out, const float* __restrict__ b_out,
    const float* __restrict__ W_k,  const float* __restrict__ W_r,
    const float* __restrict__ b_gru,
    float* __restrict__ dout,
    _Float16* __restrict__ hH, _Float16* __restrict__ hL,
    _Float16* __restrict__ oH, _Float16* __restrict__ oL,
    unsigned* __restrict__ bar)
{
    extern __shared__ _Float16 ldsh[];
    _Float16* WAh = ldsh;              // 16384 halves = 32KB
    _Float16* WAl = ldsh + 16384;
    _Float16* WBh = ldsh + 32768;
    _Float16* WBl = ldsh + 49152;
    float*    mhs = (float*)(ldsh + 65536);   // [256][12] fp32 = 12KB

    const int b    = blockIdx.x;
    const int tid  = threadIdx.x;
    const int wv   = tid >> 6;         // wave 0..7
    const int lane = tid & 63;
    const int nn   = lane & 15;        // fragment n / C col
    const int kq   = lane >> 4;        // fragment k-quad / C row-quad

    // ---------- one-time: pack weight panels into LDS fragment order -------
    // phase-A panel col n: n<4 -> W_out col 4b+n
    //                      n>=4: q=n-4, jj=q/3, ch=q%3 -> W_r col ch*1024+4b+jj
    for (int idx = tid; idx < 16384; idx += 512) {
        const int k = idx >> 4, n = idx & 15;
        float w;
        if (n < 4) {
            w = W_out[(size_t)k * HDIM + 4 * b + n];
        } else {
            const int q = n - 4, jj = q / 3, ch = q - 3 * jj;
            w = W_r[(size_t)k * TH3 + ch * 1024 + 4 * b + jj];
        }
        const int hw = ((k >> 5) * 64 + n + (((k & 31) >> 3) << 4)) * 8 + (k & 7);
        split16(w, &WAh[hw], &WAl[hw]);
    }
    for (int idx = tid; idx < 16384; idx += 512) {
        const int k = idx >> 4, n = idx & 15;
        float w = 0.0f;
        if (n < 12) {
            const int jj = n / 3, ch = n - 3 * jj;
            w = W_k[(size_t)k * TH3 + ch * 1024 + 4 * b + jj];
        }
        const int hw = ((k >> 5) * 64 + n + (((k & 31) >> 3) << 4)) * 8 + (k & 7);
        split16(w, &WBh[hw], &WBl[hw]);
    }

    // ---------- per-lane biases ----------
    float bA;
    if (nn < 4) {
        bA = b_out[4 * b + nn];
    } else {
        const int q = nn - 4, jj = q / 3, ch = q - 3 * jj;
        bA = b_gru[TH3 + ch * 1024 + 4 * b + jj];   // recurrent bias b_gru[1]
    }
    float bB = 0.0f;                                 // phase-B col bias (b_gru[0])
    if (nn < 12) {
        const int jj = nn / 3, ch = nn - 3 * jj;
        bB = b_gru[ch * 1024 + 4 * b + jj];
    }

    // ---------- phase 0: h0 = tanh(x @ W_fs + b_fs), 4 cols/block ----------
    {
        const int row = tid & 255;
        const int c = 4 * b + ((tid >> 8) << 1);     // 2 cols per thread
        float a0 = 0.0f, a1 = 0.0f;
        const float* xr = x + (size_t)row * HDIM;
        for (int k = 0; k < HDIM; k += 4) {
            const float4 xv = *(const float4*)(xr + k);
#pragma unroll
            for (int kk = 0; kk < 4; ++kk) {
                const float2 wv2 = *(const float2*)(W_fs + (size_t)(k + kk) * HDIM + c);
                const float av = (&xv.x)[kk];
                a0 = fmaf(av, wv2.x, a0);
                a1 = fmaf(av, wv2.y, a1);
            }
        }
        const float h0 = tanhf(a0 + b_fs[c]);
        const float h1 = tanhf(a1 + b_fs[c + 1]);
        _Float16 hi, lo;
        split16(h0, &hi, &lo);
        st_h16(&hH[frag_idx(row, c)], hi);
        st_h16(&hL[frag_idx(row, c)], lo);
        split16(h1, &hi, &lo);
        st_h16(&hH[frag_idx(row, c + 1)], hi);
        st_h16(&hL[frag_idx(row, c + 1)], lo);
    }
    unsigned gen = 0;
    gbar(bar, ++gen);

    const int mt0 = 2 * wv, mt1 = 2 * wv + 1;        // this wave's m-tiles
    float hreg[2][4];                                // gate lanes' fp32 h state

    // ---------- recurrence ----------
    for (int t = 0; ; ++t) {
        // ===== phase A: [out(4) | mh(12)] = h @ [W_out sel | W_r sel] =====
        {
            float4v aH0 = {0.f,0.f,0.f,0.f}, aXa0 = {0.f,0.f,0.f,0.f}, aXb0 = {0.f,0.f,0.f,0.f};
            float4v aH1 = {0.f,0.f,0.f,0.f}, aXa1 = {0.f,0.f,0.f,0.f}, aXb1 = {0.f,0.f,0.f,0.f};
            gemm_panel((const half8*)hH, (const half8*)hL, WAh, WAl,
                       mt0, mt1, lane, aH0, aXa0, aXb0, aH1, aXa1, aXb1);
#pragma unroll
            for (int m = 0; m < 2; ++m) {
                const int mt = (m == 0) ? mt0 : mt1;
#pragma unroll
                for (int r = 0; r < 4; ++r) {
                    const int row = mt * 16 + kq * 4 + r;
                    float v = ((m == 0) ? aH0[r] + (aXa0[r] + aXb0[r]) * RINV
                                        : aH1[r] + (aXa1[r] + aXb1[r]) * RINV) + bA;
                    if (nn < 4) {
                        v = fmaxf(v, 0.0f);
                        if (t < TSTEPS) {
                            _Float16 hi, lo;
                            split16(v, &hi, &lo);
                            const int fi = frag_idx(row, 4 * b + nn);
                            st_h16(&oH[fi], hi);
                            st_h16(&oL[fi], lo);
                        }
                    } else if (t < TSTEPS) {
                        mhs[row * 12 + (nn - 4)] = v;   // mh stays in LDS
                    }
                }
            }
            if (t == TSTEPS) {
                // final out column -> dout col T-1, then done
                if (nn < 4) {
#pragma unroll
                    for (int m = 0; m < 2; ++m) {
                        const int mt = (m == 0) ? mt0 : mt1;
#pragma unroll
                        for (int r = 0; r < 4; ++r) {
                            const int row = mt * 16 + kq * 4 + r;
                            const float v = fmaxf(((m == 0) ? aH0[r] + (aXa0[r] + aXb0[r]) * RINV
                                                            : aH1[r] + (aXa1[r] + aXb1[r]) * RINV) + bA, 0.0f);
                            __builtin_nontemporal_store(
                                v, &dout[(size_t)row * (TSTEPS * HDIM) +
                                         (size_t)(TSTEPS - 1) * HDIM + 4 * b + nn]);
                        }
                    }
                }
                break;
            }
            gbar_arrive(bar, ++gen);
            // private dout stores hide under the barrier spin
            if (nn < 4 && t >= 1) {
#pragma unroll
                for (int m = 0; m < 2; ++m) {
                    const int mt = (m == 0) ? mt0 : mt1;
#pragma unroll
                    for (int r = 0; r < 4; ++r) {
                        const int row = mt * 16 + kq * 4 + r;
                        const float v = fmaxf(((m == 0) ? aH0[r] + (aXa0[r] + aXb0[r]) * RINV
                                                        : aH1[r] + (aXa1[r] + aXb1[r]) * RINV) + bA, 0.0f);
                        __builtin_nontemporal_store(
                            v, &dout[(size_t)row * (TSTEPS * HDIM) +
                                     (size_t)(t - 1) * HDIM + 4 * b + nn]);
                    }
                }
            }
            gbar_wait(bar, gen);
        }

        // ===== phase B: mx = out @ W_k + fused GRU gates -> h planes =====
        {
            float4v aH0 = {0.f,0.f,0.f,0.f}, aXa0 = {0.f,0.f,0.f,0.f}, aXb0 = {0.f,0.f,0.f,0.f};
            float4v aH1 = {0.f,0.f,0.f,0.f}, aXa1 = {0.f,0.f,0.f,0.f}, aXb1 = {0.f,0.f,0.f,0.f};
            gemm_panel((const half8*)oH, (const half8*)oL, WBh, WBl,
                       mt0, mt1, lane, aH0, aXa0, aXb0, aH1, aXa1, aXb1);
            // per-lane mx values (col nn), bias folded
            float vals[2][4], v1[2][4], v2[2][4];
#pragma unroll
            for (int r = 0; r < 4; ++r) {
                vals[0][r] = aH0[r] + (aXa0[r] + aXb0[r]) * RINV + bB;
                vals[1][r] = aH1[r] + (aXa1[r] + aXb1[r]) * RINV + bB;
            }
            // gather r-gate (col+1) and h-gate (col+2) values to z-lanes
#pragma unroll
            for (int m = 0; m < 2; ++m)
#pragma unroll
                for (int r = 0; r < 4; ++r) {
                    v1[m][r] = __shfl(vals[m][r], (lane + 1) & 63);
                    v2[m][r] = __shfl(vals[m][r], (lane + 2) & 63);
                }
            if (nn < 12 && (nn % 3) == 0) {
                const int jj = nn / 3;
                const int j = 4 * b + jj;
                if (t == 0) {
#pragma unroll
                    for (int m = 0; m < 2; ++m)
#pragma unroll
                        for (int r = 0; r < 4; ++r) {
                            const int mt = (m == 0) ? mt0 : mt1;
                            const int row = mt * 16 + kq * 4 + r;
                            const int fi = frag_idx(row, j);
                            hreg[m][r] = (float)hH[fi] + (float)hL[fi] * RINV;
                        }
                }
#pragma unroll
                for (int m = 0; m < 2; ++m) {
                    const int mt = (m == 0) ? mt0 : mt1;
#pragma unroll
                    for (int r = 0; r < 4; ++r) {
                        const int row = mt * 16 + kq * 4 + r;
                        const float* mrow = &mhs[row * 12 + 3 * jj];
                        const float z    = sigmoidf_(vals[m][r] + mrow[0]);
                        const float rg   = sigmoidf_(v1[m][r] + mrow[1]);
                        const float cand = tanhf(v2[m][r] + rg * mrow[2]);
                        const float hn = z * hreg[m][r] + (1.0f - z) * cand;
                        hreg[m][r] = hn;
                        const int fi = frag_idx(row, j);
                        _Float16 hi, lo;
                        split16(hn, &hi, &lo);
                        st_h16(&hH[fi], hi);
                        st_h16(&hL[fi], lo);
                    }
                }
            }
            gbar(bar, ++gen);
        }
    }
}

// ===========================================================================
// Fallback path (round-2 kernels) — used only if cooperative launch fails.
// ===========================================================================
__global__ __launch_bounds__(128) void gemmA(
    const float* __restrict__ A,
    const float* __restrict__ W0, const float* __restrict__ b0, int act0,
    float* __restrict__ C0, float* __restrict__ C2,
    const float* __restrict__ W1, const float* __restrict__ b1,
    float* __restrict__ C1)
{
    __shared__ __align__(16) float Ass[32][36];
    __shared__ __align__(16) float Ws[32][68];
    const int tid = threadIdx.x;
    const int bx = blockIdx.x, by = blockIdx.y;
    const int r0 = by * 32;
    const bool reg0 = (bx < 16);
    const int c0 = reg0 ? bx * 64 : (bx - 16) * 64;
    const float* __restrict__ W = reg0 ? W0 : W1;
    const int ldw = reg0 ? 1024 : 3072;
    const int arow = tid >> 2;
    const int ak   = (tid & 3) << 2;
    const int wrow = tid >> 4;
    const int wcol = (tid & 15) << 2;
    const int ty = tid >> 4;
    const int tx = tid & 15;
    float acc[4][4] = {};
    const float* Ap = A + (size_t)(r0 + arow) * 1024 + ak;
    const float* Wp = W + (size_t)wrow * ldw + c0 + wcol;
    for (int k0 = 0; k0 < 1024; k0 += 32) {
        const float4 a0 = *(const float4*)(Ap + k0);
        const float4 a1 = *(const float4*)(Ap + k0 + 16);
        const float4 w0 = *(const float4*)(Wp + (size_t)k0 * ldw);
        const float4 w1 = *(const float4*)(Wp + (size_t)(k0 + 8) * ldw);
        const float4 w2 = *(const float4*)(Wp + (size_t)(k0 + 16) * ldw);
        const float4 w3 = *(const float4*)(Wp + (size_t)(k0 + 24) * ldw);
        __syncthreads();
        Ass[ak + 0][arow] = a0.x; Ass[ak + 1][arow] = a0.y;
        Ass[ak + 2][arow] = a0.z; Ass[ak + 3][arow] = a0.w;
        Ass[ak + 16][arow] = a1.x; Ass[ak + 17][arow] = a1.y;
        Ass[ak + 18][arow] = a1.z; Ass[ak + 19][arow] = a1.w;
        *(float4*)&Ws[wrow][wcol]      = w0;
        *(float4*)&Ws[wrow + 8][wcol]  = w1;
        *(float4*)&Ws[wrow + 16][wcol] = w2;
        *(float4*)&Ws[wrow + 24][wcol] = w3;
        __syncthreads();
#pragma unroll
        for (int kk = 0; kk < 32; ++kk) {
            const float4 a4 = *(const float4*)&Ass[kk][ty << 2];
            const float4 w4 = *(const float4*)&Ws[kk][tx << 2];
            const float a[4] = {a4.x, a4.y, a4.z, a4.w};
            const float w[4] = {w4.x, w4.y, w4.z, w4.w};
#pragma unroll
            for (int i = 0; i < 4; ++i)
#pragma unroll
                for (int j = 0; j < 4; ++j)
                    acc[i][j] = fmaf(a[i], w[j], acc[i][j]);
        }
    }
    const float* bias = reg0 ? b0 : b1;
    const float4 bv = *(const float4*)(bias + c0 + (tx << 2));
    const float bb[4] = {bv.x, bv.y, bv.z, bv.w};
#pragma unroll
    for (int i = 0; i < 4; ++i) {
        const int row = r0 + (ty << 2) + i;
        float v[4];
#pragma unroll
        for (int j = 0; j < 4; ++j) {
            float tv = acc[i][j] + bb[j];
            if (reg0) { tv = (act0 == 1) ? fmaxf(tv, 0.0f) : tanhf(tv); }
            v[j] = tv;
        }
        const float4 o = make_float4(v[0], v[1], v[2], v[3]);
        if (reg0) {
            *(float4*)(C0 + (size_t)row * 1024 + c0 + (tx << 2)) = o;
            if (C2)
                *(float4*)(C2 + (size_t)row * (TSTEPS * HDIM) + c0 + (tx << 2)) = o;
        } else {
            *(float4*)(C1 + (size_t)row * TH3 + c0 + (tx << 2)) = o;
        }
    }
}

__global__ __launch_bounds__(128) void gemmB(
    const float* __restrict__ A,
    const float* __restrict__ Wk,
    const float* __restrict__ bg,
    const float* __restrict__ mh,
    float* __restrict__ h)
{
    __shared__ __align__(16) float Ass[32][36];
    __shared__ __align__(16) float Ws[3][32][20];
    const int tid = threadIdx.x;
    const int j0 = blockIdx.x * 16;
    const int r0 = blockIdx.y * 32;
    const int arow = tid >> 2;
    const int ak   = (tid & 3) << 2;
    const int wr   = tid >> 2;
    const int wc   = (tid & 3) << 2;
    const int ty = tid >> 4;
    const int tx = tid & 15;
    float acc[3][4] = {};
    const float* Ap = A + (size_t)(r0 + arow) * 1024 + ak;
    const float* Wp = Wk + (size_t)wr * TH3 + j0 + wc;
    for (int k0 = 0; k0 < 1024; k0 += 32) {
        const float4 a0 = *(const float4*)(Ap + k0);
        const float4 a1 = *(const float4*)(Ap + k0 + 16);
        float4 wv[3];
#pragma unroll
        for (int c = 0; c < 3; ++c)
            wv[c] = *(const float4*)(Wp + (size_t)k0 * TH3 + c * 1024);
        __syncthreads();
        Ass[ak + 0][arow] = a0.x; Ass[ak + 1][arow] = a0.y;
        Ass[ak + 2][arow] = a0.z; Ass[ak + 3][arow] = a0.w;
        Ass[ak + 16][arow] = a1.x; Ass[ak + 17][arow] = a1.y;
        Ass[ak + 18][arow] = a1.z; Ass[ak + 19][arow] = a1.w;
#pragma unroll
        for (int c = 0; c < 3; ++c)
            *(float4*)&Ws[c][wr][wc] = wv[c];
        __syncthreads();
#pragma unroll
        for (int kk = 0; kk < 32; ++kk) {
            const float4 a4 = *(const float4*)&Ass[kk][ty << 2];
            const float a[4] = {a4.x, a4.y, a4.z, a4.w};
            const float wz = Ws[0][kk][tx];
            const float wr_ = Ws[1][kk][tx];
            const float wh = Ws[2][kk][tx];
#pragma unroll
            for (int i = 0; i < 4; ++i) {
                acc[0][i] = fmaf(a[i], wz, acc[0][i]);
                acc[1][i] = fmaf(a[i], wr_, acc[1][i]);
                acc[2][i] = fmaf(a[i], wh, acc[2][i]);
            }
        }
    }
    const int j = j0 + tx;
    const float bz = bg[j];
    const float br = bg[HDIM + j];
    const float bh = bg[2 * HDIM + j];
#pragma unroll
    for (int i = 0; i < 4; ++i) {
        const int row = r0 + (ty << 2) + i;
        const float* mhp = mh + (size_t)row * TH3;
        const float z  = sigmoidf_(acc[0][i] + bz + mhp[j]);
        const float rg = sigmoidf_(acc[1][i] + br + mhp[HDIM + j]);
        const float cand = tanhf(acc[2][i] + bh + rg * mhp[2 * HDIM + j]);
        const size_t hi = (size_t)row * HDIM + j;
        const float ho = h[hi];
        h[hi] = z * ho + (1.0f - z) * cand;
    }
}

extern "C" void kernel_launch(void* const* d_in, const int* in_sizes, int n_in,
                              void* d_out, int out_size, void* d_ws, size_t ws_size,
                              hipStream_t stream) {
    const float* x     = (const float*)d_in[0];
    const float* W_fs  = (const float*)d_in[1];
    const float* b_fs  = (const float*)d_in[2];
    const float* W_out = (const float*)d_in[3];
    const float* b_out = (const float*)d_in[4];
    const float* W_k   = (const float*)d_in[5];
    const float* W_r   = (const float*)d_in[6];
    const float* b_gru = (const float*)d_in[7];
    float* out = (float*)d_out;            // [B, T, H]

    char* ws = (char*)d_ws;
    _Float16* hH = (_Float16*)(ws);                  // 512KB each plane
    _Float16* hL = (_Float16*)(ws + 512 * 1024);
    _Float16* oH = (_Float16*)(ws + 1024 * 1024);
    _Float16* oL = (_Float16*)(ws + 1536 * 1024);
    unsigned* bar = (unsigned*)(ws + 2048 * 1024);   // barrier counters (2KB)

    // barrier counters must start at 0 every launch (graph-capture safe)
    hipMemsetAsync(bar, 0, 2048, stream);

    void* args[] = {
        (void*)&x, (void*)&W_fs, (void*)&b_fs, (void*)&W_out, (void*)&b_out,
        (void*)&W_k, (void*)&W_r, (void*)&b_gru, (void*)&out,
        (void*)&hH, (void*)&hL, (void*)&oH, (void*)&oL, (void*)&bar
    };
    const size_t lds_bytes = 131072 + 12288;         // panels 128KB + mhs 12KB
    hipError_t err = hipLaunchCooperativeKernel(
        (const void*)decoder_mfma, dim3(256), dim3(512),
        args, lds_bytes, stream);

    if (err != hipSuccess) {
        // fallback: round-2 multi-launch fp32 path
        float* h    = (float*)d_ws;
        float* outb = h    + BROWS * HDIM;
        float* mhf  = outb + BROWS * HDIM;
        const dim3 blk(128);
        const dim3 gridInit(16, 8);
        const dim3 gridA(64, 8);
        const dim3 gridB(64, 8);
        gemmA<<<gridInit, blk, 0, stream>>>(x, W_fs, b_fs, 2, h, nullptr,
                                            nullptr, nullptr, nullptr);
        for (int t = 0; t < TSTEPS; ++t) {
            float* c2 = (t >= 1) ? (out + (size_t)(t - 1) * HDIM) : nullptr;
            gemmA<<<gridA, blk, 0, stream>>>(h, W_out, b_out, 1, outb, c2,
                                             W_r, b_gru + TH3, mhf);
            gemmB<<<gridB, blk, 0, stream>>>(outb, W_k, b_gru, mhf, h);
        }
        gemmA<<<gridInit, blk, 0, stream>>>(h, W_out, b_out, 1, outb,
                                            out + (size_t)(TSTEPS - 1) * HDIM,
                                            nullptr, nullptr, nullptr);
    }
}

// Round 3
// 9137.479 us; speedup vs baseline: 1.2807x; 1.2807x over previous
//
#include <hip/hip_runtime.h>
#include <math.h>

#define HDIM 1024
#define BROWS 256
#define TSTEPS 64
#define TH3 3072
#define RSCALE 1024.0f
#define RINV   0.0009765625f   // 2^-10

typedef _Float16 half8 __attribute__((ext_vector_type(8)));
typedef float float4v __attribute__((ext_vector_type(4)));

__device__ __forceinline__ float sigmoidf_(float x) {
    return 1.0f / (1.0f + __expf(-x));
}

__device__ __forceinline__ float4v mfma16(half8 a, half8 b, float4v c) {
    return __builtin_amdgcn_mfma_f32_16x16x32_f16(a, b, c, 0, 0, 0);
}

// halfword index of element (m,k) in a [256][1024] plane stored in MFMA
// A-fragment order: [mtile][ktile][lane][slot], lane=(m&15)+16*((k&31)>>3),
// slot=k&7. A wave's (mtile,ktile) fragment is 1KB contiguous.
__device__ __forceinline__ int frag_idx(int m, int k) {
    return (((m >> 4) * 32 + (k >> 5)) * 64 + ((m & 15) + (((k & 31) >> 3) << 4))) * 8 + (k & 7);
}

__device__ __forceinline__ void split16(float v, _Float16* hp, _Float16* lp) {
    const _Float16 h = (_Float16)v;
    *hp = h;
    *lp = (_Float16)((v - (float)h) * RSCALE);
}

// Write-through 2-byte store: sc0 sc1 -> bypasses L1/L2 to the device
// coherence point. L2 never holds dirty shared lines, so the grid barrier
// needs no writeback walk.
__device__ __forceinline__ void st_h16(_Float16* p, _Float16 v) {
    const unsigned u = (unsigned)__builtin_bit_cast(unsigned short, v);
    asm volatile("global_store_short %0, %1, off sc0 sc1"
                 :: "v"(p), "v"(u) : "memory");
}

// ---------------------------------------------------------------------------
// Split grid barrier (256 blocks = 8 groups x 32), CASCADE-FREE ordering:
//   vmcnt(0) -> __syncthreads -> buffer_inv (acquire fence) -> arrive -> spin.
// The L2 invalidate executes BEFORE arrival, so barrier release (root hit)
// implies ALL 256 blocks have already invalidated. Post-release loads can
// never be killed by a late block's inv -> L2 retains the broadcast fills.
// (Round-2 lesson: inv-after-spin caused a serial invalidate-refetch cascade
//  across the 32 CUs of each XCD: FETCH 0.67GB -> 7.6GB.)
// Staleness proof for the 2-phase ping-pong (A reads h, writes o; B reads o,
// writes h): lines a laggard re-caches during phase P are re-read only in
// phase P+2; its own inv at barrier P+1 (after its P+1 work, which touches
// only the other buffer) kills them first.
// ---------------------------------------------------------------------------
__device__ __forceinline__ void gbar_arrive(unsigned* bar, unsigned gen) {
    asm volatile("s_waitcnt vmcnt(0)" ::: "memory");
    __syncthreads();
    __builtin_amdgcn_fence(__ATOMIC_ACQUIRE, "agent");   // buffer_inv, pre-spin
    if (threadIdx.x == 0) {
        unsigned* gc = bar + ((blockIdx.x & 7) << 5);   // 128B-separated group counters
        unsigned* rc = bar + 256;                       // root counter (own line)
        const unsigned old = __hip_atomic_fetch_add(gc, 1u, __ATOMIC_RELAXED,
                                                    __HIP_MEMORY_SCOPE_AGENT);
        if (old + 1u == gen * 32u)
            __hip_atomic_fetch_add(rc, 1u, __ATOMIC_RELAXED,
                                   __HIP_MEMORY_SCOPE_AGENT);
    }
}

__device__ __forceinline__ void gbar_wait(unsigned* bar, unsigned gen) {
    if (threadIdx.x == 0) {
        unsigned* rc = bar + 256;
        while (__hip_atomic_load(rc, __ATOMIC_RELAXED,
                                 __HIP_MEMORY_SCOPE_AGENT) < gen * 8u)
            __builtin_amdgcn_s_sleep(1);
    }
    __syncthreads();
}

__device__ __forceinline__ void gbar(unsigned* bar, unsigned gen) {
    gbar_arrive(bar, gen);
    gbar_wait(bar, gen);
}

// ---------------------------------------------------------------------------
// 3-pass split-fp16 GEMM panel, register double-buffered, chunk = 2 k-tiles
// (8 lane-loads in flight; rA = 16 half8 = 64 VGPRs so the compiler can keep
// it in registers -- round-2's chunk=4 (128 VGPRs) got clamped/serialized).
// All rA indices are compile-time (full unroll) so the array stays in VGPRs.
// ---------------------------------------------------------------------------
__device__ __forceinline__ void gemm_panel(
    const half8* __restrict__ AH, const half8* __restrict__ AL,
    const _Float16* __restrict__ WH, const _Float16* __restrict__ WL,
    int mt0, int mt1, int lane,
    float4v& aH0, float4v& aXa0, float4v& aXb0,
    float4v& aH1, float4v& aXa1, float4v& aXb1)
{
    half8 rA[2][2][4];
    const int base0 = mt0 * 32 * 64 + lane;
    const int base1 = mt1 * 32 * 64 + lane;
    const int lofs = lane * 8;
#pragma unroll
    for (int kk = 0; kk < 2; ++kk) {
        rA[0][kk][0] = AH[base0 + kk * 64];
        rA[0][kk][1] = AL[base0 + kk * 64];
        rA[0][kk][2] = AH[base1 + kk * 64];
        rA[0][kk][3] = AL[base1 + kk * 64];
    }
#pragma unroll
    for (int c = 0; c < 16; ++c) {
        if (c < 15) {
#pragma unroll
            for (int kk = 0; kk < 2; ++kk) {
                const int kt = (c + 1) * 2 + kk;
                rA[(c + 1) & 1][kk][0] = AH[base0 + kt * 64];
                rA[(c + 1) & 1][kk][1] = AL[base0 + kt * 64];
                rA[(c + 1) & 1][kk][2] = AH[base1 + kt * 64];
                rA[(c + 1) & 1][kk][3] = AL[base1 + kt * 64];
            }
        }
#pragma unroll
        for (int kk = 0; kk < 2; ++kk) {
            const int kt = c * 2 + kk;
            const half8 bh = *(const half8*)&WH[kt * 512 + lofs];
            const half8 bl = *(const half8*)&WL[kt * 512 + lofs];
            const half8 a0h = rA[c & 1][kk][0];
            const half8 a0l = rA[c & 1][kk][1];
            const half8 a1h = rA[c & 1][kk][2];
            const half8 a1l = rA[c & 1][kk][3];
            aH0  = mfma16(a0h, bh, aH0);
            aXa0 = mfma16(a0l, bh, aXa0);
            aXb0 = mfma16(a0h, bl, aXb0);
            aH1  = mfma16(a1h, bh, aH1);
            aXa1 = mfma16(a1l, bh, aXa1);
            aXb1 = mfma16(a1h, bl, aXb1);
        }
    }
}

// ===========================================================================
// Persistent cooperative kernel: 256 blocks x 512 threads (8 waves, 2/SIMD).
// LDS 140KB: WAh/WAl = phase-A panel [4 cols W_out | 12 W_r gate cols of
//            THIS block] as split-fp16 B-fragments;
//            WBh/WBl = 12 interleaved gate cols of W_k; mhs = [256][12] fp32.
// Activations in global as split-fp16 A-fragment planes (hH/hL, oH/oL),
// written through (sc0 sc1); mh never leaves the block (LDS); h state kept
// in registers by the gate lanes. Cascade-free grid barrier; register-
// pipelined k-loops for memory-level parallelism.
// ===========================================================================
__global__ __launch_bounds__(512, 2) void decoder_mfma(
    const float* __restrict__ x,
    const float* __restrict__ W_fs, const float* __restrict__ b_fs,
    const float* __restrict__ W_out, const float* __restrict__ b_out,
    const float* __restrict__ W_k,  const float* __restrict__ W_r,
    const float* __restrict__ b_gru,
    float* __restrict__ dout,
    _Float16* __restrict__ hH, _Float16* __restrict__ hL,
    _Float16* __restrict__ oH, _Float16* __restrict__ oL,
    unsigned* __restrict__ bar)
{
    extern __shared__ _Float16 ldsh[];
    _Float16* WAh = ldsh;              // 16384 halves = 32KB
    _Float16* WAl = ldsh + 16384;
    _Float16* WBh = ldsh + 32768;
    _Float16* WBl = ldsh + 49152;
    float*    mhs = (float*)(ldsh + 65536);   // [256][12] fp32 = 12KB

    const int b    = blockIdx.x;
    const int tid  = threadIdx.x;
    const int wv   = tid >> 6;         // wave 0..7
    const int lane = tid & 63;
    const int nn   = lane & 15;        // fragment n / C col
    const int kq   = lane >> 4;        // fragment k-quad / C row-quad

    // ---------- one-time: pack weight panels into LDS fragment order -------
    // phase-A panel col n: n<4 -> W_out col 4b+n
    //                      n>=4: q=n-4, jj=q/3, ch=q%3 -> W_r col ch*1024+4b+jj
    for (int idx = tid; idx < 16384; idx += 512) {
        const int k = idx >> 4, n = idx & 15;
        float w;
        if (n < 4) {
            w = W_out[(size_t)k * HDIM + 4 * b + n];
        } else {
            const int q = n - 4, jj = q / 3, ch = q - 3 * jj;
            w = W_r[(size_t)k * TH3 + ch * 1024 + 4 * b + jj];
        }
        const int hw = ((k >> 5) * 64 + n + (((k & 31) >> 3) << 4)) * 8 + (k & 7);
        split16(w, &WAh[hw], &WAl[hw]);
    }
    for (int idx = tid; idx < 16384; idx += 512) {
        const int k = idx >> 4, n = idx & 15;
        float w = 0.0f;
        if (n < 12) {
            const int jj = n / 3, ch = n - 3 * jj;
            w = W_k[(size_t)k * TH3 + ch * 1024 + 4 * b + jj];
        }
        const int hw = ((k >> 5) * 64 + n + (((k & 31) >> 3) << 4)) * 8 + (k & 7);
        split16(w, &WBh[hw], &WBl[hw]);
    }

    // ---------- per-lane biases ----------
    float bA;
    if (nn < 4) {
        bA = b_out[4 * b + nn];
    } else {
        const int q = nn - 4, jj = q / 3, ch = q - 3 * jj;
        bA = b_gru[TH3 + ch * 1024 + 4 * b + jj];   // recurrent bias b_gru[1]
    }
    float bB = 0.0f;                                 // phase-B col bias (b_gru[0])
    if (nn < 12) {
        const int jj = nn / 3, ch = nn - 3 * jj;
        bB = b_gru[ch * 1024 + 4 * b + jj];
    }

    // ---------- phase 0: h0 = tanh(x @ W_fs + b_fs), 4 cols/block ----------
    {
        const int row = tid & 255;
        const int c = 4 * b + ((tid >> 8) << 1);     // 2 cols per thread
        float a0 = 0.0f, a1 = 0.0f;
        const float* xr = x + (size_t)row * HDIM;
        for (int k = 0; k < HDIM; k += 4) {
            const float4 xv = *(const float4*)(xr + k);
#pragma unroll
            for (int kk = 0; kk < 4; ++kk) {
                const float2 wv2 = *(const float2*)(W_fs + (size_t)(k + kk) * HDIM + c);
                const float av = (&xv.x)[kk];
                a0 = fmaf(av, wv2.x, a0);
                a1 = fmaf(av, wv2.y, a1);
            }
        }
        const float h0 = tanhf(a0 + b_fs[c]);
        const float h1 = tanhf(a1 + b_fs[c + 1]);
        _Float16 hi, lo;
        split16(h0, &hi, &lo);
        st_h16(&hH[frag_idx(row, c)], hi);
        st_h16(&hL[frag_idx(row, c)], lo);
        split16(h1, &hi, &lo);
        st_h16(&hH[frag_idx(row, c + 1)], hi);
        st_h16(&hL[frag_idx(row, c + 1)], lo);
    }
    unsigned gen = 0;
    gbar(bar, ++gen);

    const int mt0 = 2 * wv, mt1 = 2 * wv + 1;        // this wave's m-tiles
    float hreg[2][4];                                // gate lanes' fp32 h state

    // ---------- recurrence ----------
    for (int t = 0; ; ++t) {
        // ===== phase A: [out(4) | mh(12)] = h @ [W_out sel | W_r sel] =====
        {
            float4v aH0 = {0.f,0.f,0.f,0.f}, aXa0 = {0.f,0.f,0.f,0.f}, aXb0 = {0.f,0.f,0.f,0.f};
            float4v aH1 = {0.f,0.f,0.f,0.f}, aXa1 = {0.f,0.f,0.f,0.f}, aXb1 = {0.f,0.f,0.f,0.f};
            gemm_panel((const half8*)hH, (const half8*)hL, WAh, WAl,
                       mt0, mt1, lane, aH0, aXa0, aXb0, aH1, aXa1, aXb1);
#pragma unroll
            for (int m = 0; m < 2; ++m) {
                const int mt = (m == 0) ? mt0 : mt1;
#pragma unroll
                for (int r = 0; r < 4; ++r) {
                    const int row = mt * 16 + kq * 4 + r;
                    float v = ((m == 0) ? aH0[r] + (aXa0[r] + aXb0[r]) * RINV
                                        : aH1[r] + (aXa1[r] + aXb1[r]) * RINV) + bA;
                    if (nn < 4) {
                        v = fmaxf(v, 0.0f);
                        if (t < TSTEPS) {
                            _Float16 hi, lo;
                            split16(v, &hi, &lo);
                            const int fi = frag_idx(row, 4 * b + nn);
                            st_h16(&oH[fi], hi);
                            st_h16(&oL[fi], lo);
                        }
                    } else if (t < TSTEPS) {
                        mhs[row * 12 + (nn - 4)] = v;   // mh stays in LDS
                    }
                }
            }
            if (t == TSTEPS) {
                // final out column -> dout col T-1, then done
                if (nn < 4) {
#pragma unroll
                    for (int m = 0; m < 2; ++m) {
                        const int mt = (m == 0) ? mt0 : mt1;
#pragma unroll
                        for (int r = 0; r < 4; ++r) {
                            const int row = mt * 16 + kq * 4 + r;
                            const float v = fmaxf(((m == 0) ? aH0[r] + (aXa0[r] + aXb0[r]) * RINV
                                                            : aH1[r] + (aXa1[r] + aXb1[r]) * RINV) + bA, 0.0f);
                            __builtin_nontemporal_store(
                                v, &dout[(size_t)row * (TSTEPS * HDIM) +
                                         (size_t)(TSTEPS - 1) * HDIM + 4 * b + nn]);
                        }
                    }
                }
                break;
            }
            gbar_arrive(bar, ++gen);
            // private dout stores hide under the barrier spin
            if (nn < 4 && t >= 1) {
#pragma unroll
                for (int m = 0; m < 2; ++m) {
                    const int mt = (m == 0) ? mt0 : mt1;
#pragma unroll
                    for (int r = 0; r < 4; ++r) {
                        const int row = mt * 16 + kq * 4 + r;
                        const float v = fmaxf(((m == 0) ? aH0[r] + (aXa0[r] + aXb0[r]) * RINV
                                                        : aH1[r] + (aXa1[r] + aXb1[r]) * RINV) + bA, 0.0f);
                        __builtin_nontemporal_store(
                            v, &dout[(size_t)row * (TSTEPS * HDIM) +
                                     (size_t)(t - 1) * HDIM + 4 * b + nn]);
                    }
                }
            }
            gbar_wait(bar, gen);
        }

        // ===== phase B: mx = out @ W_k + fused GRU gates -> h planes =====
        {
            float4v aH0 = {0.f,0.f,0.f,0.f}, aXa0 = {0.f,0.f,0.f,0.f}, aXb0 = {0.f,0.f,0.f,0.f};
            float4v aH1 = {0.f,0.f,0.f,0.f}, aXa1 = {0.f,0.f,0.f,0.f}, aXb1 = {0.f,0.f,0.f,0.f};
            gemm_panel((const half8*)oH, (const half8*)oL, WBh, WBl,
                       mt0, mt1, lane, aH0, aXa0, aXb0, aH1, aXa1, aXb1);
            // per-lane mx values (col nn), bias folded
            float vals[2][4], v1[2][4], v2[2][4];
#pragma unroll
            for (int r = 0; r < 4; ++r) {
                vals[0][r] = aH0[r] + (aXa0[r] + aXb0[r]) * RINV + bB;
                vals[1][r] = aH1[r] + (aXa1[r] + aXb1[r]) * RINV + bB;
            }
            // gather r-gate (col+1) and h-gate (col+2) values to z-lanes
#pragma unroll
            for (int m = 0; m < 2; ++m)
#pragma unroll
                for (int r = 0; r < 4; ++r) {
                    v1[m][r] = __shfl(vals[m][r], (lane + 1) & 63);
                    v2[m][r] = __shfl(vals[m][r], (lane + 2) & 63);
                }
            if (nn < 12 && (nn % 3) == 0) {
                const int jj = nn / 3;
                const int j = 4 * b + jj;
                if (t == 0) {
#pragma unroll
                    for (int m = 0; m < 2; ++m)
#pragma unroll
                        for (int r = 0; r < 4; ++r) {
                            const int mt = (m == 0) ? mt0 : mt1;
                            const int row = mt * 16 + kq * 4 + r;
                            const int fi = frag_idx(row, j);
                            hreg[m][r] = (float)hH[fi] + (float)hL[fi] * RINV;
                        }
                }
#pragma unroll
                for (int m = 0; m < 2; ++m) {
                    const int mt = (m == 0) ? mt0 : mt1;
#pragma unroll
                    for (int r = 0; r < 4; ++r) {
                        const int row = mt * 16 + kq * 4 + r;
                        const float* mrow = &mhs[row * 12 + 3 * jj];
                        const float z    = sigmoidf_(vals[m][r] + mrow[0]);
                        const float rg   = sigmoidf_(v1[m][r] + mrow[1]);
                        const float cand = tanhf(v2[m][r] + rg * mrow[2]);
                        const float hn = z * hreg[m][r] + (1.0f - z) * cand;
                        hreg[m][r] = hn;
                        const int fi = frag_idx(row, j);
                        _Float16 hi, lo;
                        split16(hn, &hi, &lo);
                        st_h16(&hH[fi], hi);
                        st_h16(&hL[fi], lo);
                    }
                }
            }
            gbar(bar, ++gen);
        }
    }
}

// ===========================================================================
// Fallback path (round-2 kernels) — used only if cooperative launch fails.
// ===========================================================================
__global__ __launch_bounds__(128) void gemmA(
    const float* __restrict__ A,
    const float* __restrict__ W0, const float* __restrict__ b0, int act0,
    float* __restrict__ C0, float* __restrict__ C2,
    const float* __restrict__ W1, const float* __restrict__ b1,
    float* __restrict__ C1)
{
    __shared__ __align__(16) float Ass[32][36];
    __shared__ __align__(16) float Ws[32][68];
    const int tid = threadIdx.x;
    const int bx = blockIdx.x, by = blockIdx.y;
    const int r0 = by * 32;
    const bool reg0 = (bx < 16);
    const int c0 = reg0 ? bx * 64 : (bx - 16) * 64;
    const float* __restrict__ W = reg0 ? W0 : W1;
    const int ldw = reg0 ? 1024 : 3072;
    const int arow = tid >> 2;
    const int ak   = (tid & 3) << 2;
    const int wrow = tid >> 4;
    const int wcol = (tid & 15) << 2;
    const int ty = tid >> 4;
    const int tx = tid & 15;
    float acc[4][4] = {};
    const float* Ap = A + (size_t)(r0 + arow) * 1024 + ak;
    const float* Wp = W + (size_t)wrow * ldw + c0 + wcol;
    for (int k0 = 0; k0 < 1024; k0 += 32) {
        const float4 a0 = *(const float4*)(Ap + k0);
        const float4 a1 = *(const float4*)(Ap + k0 + 16);
        const float4 w0 = *(const float4*)(Wp + (size_t)k0 * ldw);
        const float4 w1 = *(const float4*)(Wp + (size_t)(k0 + 8) * ldw);
        const float4 w2 = *(const float4*)(Wp + (size_t)(k0 + 16) * ldw);
        const float4 w3 = *(const float4*)(Wp + (size_t)(k0 + 24) * ldw);
        __syncthreads();
        Ass[ak + 0][arow] = a0.x; Ass[ak + 1][arow] = a0.y;
        Ass[ak + 2][arow] = a0.z; Ass[ak + 3][arow] = a0.w;
        Ass[ak + 16][arow] = a1.x; Ass[ak + 17][arow] = a1.y;
        Ass[ak + 18][arow] = a1.z; Ass[ak + 19][arow] = a1.w;
        *(float4*)&Ws[wrow][wcol]      = w0;
        *(float4*)&Ws[wrow + 8][wcol]  = w1;
        *(float4*)&Ws[wrow + 16][wcol] = w2;
        *(float4*)&Ws[wrow + 24][wcol] = w3;
        __syncthreads();
#pragma unroll
        for (int kk = 0; kk < 32; ++kk) {
            const float4 a4 = *(const float4*)&Ass[kk][ty << 2];
            const float4 w4 = *(const float4*)&Ws[kk][tx << 2];
            const float a[4] = {a4.x, a4.y, a4.z, a4.w};
            const float w[4] = {w4.x, w4.y, w4.z, w4.w};
#pragma unroll
            for (int i = 0; i < 4; ++i)
#pragma unroll
                for (int j = 0; j < 4; ++j)
                    acc[i][j] = fmaf(a[i], w[j], acc[i][j]);
        }
    }
    const float* bias = reg0 ? b0 : b1;
    const float4 bv = *(const float4*)(bias + c0 + (tx << 2));
    const float bb[4] = {bv.x, bv.y, bv.z, bv.w};
#pragma unroll
    for (int i = 0; i < 4; ++i) {
        const int row = r0 + (ty << 2) + i;
        float v[4];
#pragma unroll
        for (int j = 0; j < 4; ++j) {
            float tv = acc[i][j] + bb[j];
            if (reg0) { tv = (act0 == 1) ? fmaxf(tv, 0.0f) : tanhf(tv); }
            v[j] = tv;
        }
        const float4 o = make_float4(v[0], v[1], v[2], v[3]);
        if (reg0) {
            *(float4*)(C0 + (size_t)row * 1024 + c0 + (tx << 2)) = o;
            if (C2)
                *(float4*)(C2 + (size_t)row * (TSTEPS * HDIM) + c0 + (tx << 2)) = o;
        } else {
            *(float4*)(C1 + (size_t)row * TH3 + c0 + (tx << 2)) = o;
        }
    }
}

__global__ __launch_bounds__(128) void gemmB(
    const float* __restrict__ A,
    const float* __restrict__ Wk,
    const float* __restrict__ bg,
    const float* __restrict__ mh,
    float* __restrict__ h)
{
    __shared__ __align__(16) float Ass[32][36];
    __shared__ __align__(16) float Ws[3][32][20];
    const int tid = threadIdx.x;
    const int j0 = blockIdx.x * 16;
    const int r0 = blockIdx.y * 32;
    const int arow = tid >> 2;
    const int ak   = (tid & 3) << 2;
    const int wr   = tid >> 2;
    const int wc   = (tid & 3) << 2;
    const int ty = tid >> 4;
    const int tx = tid & 15;
    float acc[3][4] = {};
    const float* Ap = A + (size_t)(r0 + arow) * 1024 + ak;
    const float* Wp = Wk + (size_t)wr * TH3 + j0 + wc;
    for (int k0 = 0; k0 < 1024; k0 += 32) {
        const float4 a0 = *(const float4*)(Ap + k0);
        const float4 a1 = *(const float4*)(Ap + k0 + 16);
        float4 wv[3];
#pragma unroll
        for (int c = 0; c < 3; ++c)
            wv[c] = *(const float4*)(Wp + (size_t)k0 * TH3 + c * 1024);
        __syncthreads();
        Ass[ak + 0][arow] = a0.x; Ass[ak + 1][arow] = a0.y;
        Ass[ak + 2][arow] = a0.z; Ass[ak + 3][arow] = a0.w;
        Ass[ak + 16][arow] = a1.x; Ass[ak + 17][arow] = a1.y;
        Ass[ak + 18][arow] = a1.z; Ass[ak + 19][arow] = a1.w;
#pragma unroll
        for (int c = 0; c < 3; ++c)
            *(float4*)&Ws[c][wr][wc] = wv[c];
        __syncthreads();
#pragma unroll
        for (int kk = 0; kk < 32; ++kk) {
            const float4 a4 = *(const float4*)&Ass[kk][ty << 2];
            const float a[4] = {a4.x, a4.y, a4.z, a4.w};
            const float wz = Ws[0][kk][tx];
            const float wr_ = Ws[1][kk][tx];
            const float wh = Ws[2][kk][tx];
#pragma unroll
            for (int i = 0; i < 4; ++i) {
                acc[0][i] = fmaf(a[i], wz, acc[0][i]);
                acc[1][i] = fmaf(a[i], wr_, acc[1][i]);
                acc[2][i] = fmaf(a[i], wh, acc[2][i]);
            }
        }
    }
    const int j = j0 + tx;
    const float bz = bg[j];
    const float br = bg[HDIM + j];
    const float bh = bg[2 * HDIM + j];
#pragma unroll
    for (int i = 0; i < 4; ++i) {
        const int row = r0 + (ty << 2) + i;
        const float* mhp = mh + (size_t)row * TH3;
        const float z  = sigmoidf_(acc[0][i] + bz + mhp[j]);
        const float rg = sigmoidf_(acc[1][i] + br + mhp[HDIM + j]);
        const float cand = tanhf(acc[2][i] + bh + rg * mhp[2 * HDIM + j]);
        const size_t hi = (size_t)row * HDIM + j;
        const float ho = h[hi];
        h[hi] = z * ho + (1.0f - z) * cand;
    }
}

extern "C" void kernel_launch(void* const* d_in, const int* in_sizes, int n_in,
                              void* d_out, int out_size, void* d_ws, size_t ws_size,
                              hipStream_t stream) {
    const float* x     = (const float*)d_in[0];
    const float* W_fs  = (const float*)d_in[1];
    const float* b_fs  = (const float*)d_in[2];
    const float* W_out = (const float*)d_in[3];
    const float* b_out = (const float*)d_in[4];
    const float* W_k   = (const float*)d_in[5];
    const float* W_r   = (const float*)d_in[6];
    const float* b_gru = (const float*)d_in[7];
    float* out = (float*)d_out;            // [B, T, H]

    char* ws = (char*)d_ws;
    _Float16* hH = (_Float16*)(ws);                  // 512KB each plane
    _Float16* hL = (_Float16*)(ws + 512 * 1024);
    _Float16* oH = (_Float16*)(ws + 1024 * 1024);
    _Float16* oL = (_Float16*)(ws + 1536 * 1024);
    unsigned* bar = (unsigned*)(ws + 2048 * 1024);   // barrier counters (2KB)

    // barrier counters must start at 0 every launch (graph-capture safe)
    hipMemsetAsync(bar, 0, 2048, stream);

    void* args[] = {
        (void*)&x, (void*)&W_fs, (void*)&b_fs, (void*)&W_out, (void*)&b_out,
        (void*)&W_k, (void*)&W_r, (void*)&b_gru, (void*)&out,
        (void*)&hH, (void*)&hL, (void*)&oH, (void*)&oL, (void*)&bar
    };
    const size_t lds_bytes = 131072 + 12288;         // panels 128KB + mhs 12KB
    hipError_t err = hipLaunchCooperativeKernel(
        (const void*)decoder_mfma, dim3(256), dim3(512),
        args, lds_bytes, stream);

    if (err != hipSuccess) {
        // fallback: round-2 multi-launch fp32 path
        float* h    = (float*)d_ws;
        float* outb = h    + BROWS * HDIM;
        float* mhf  = outb + BROWS * HDIM;
        const dim3 blk(128);
        const dim3 gridInit(16, 8);
        const dim3 gridA(64, 8);
        const dim3 gridB(64, 8);
        gemmA<<<gridInit, blk, 0, stream>>>(x, W_fs, b_fs, 2, h, nullptr,
                                            nullptr, nullptr, nullptr);
        for (int t = 0; t < TSTEPS; ++t) {
            float* c2 = (t >= 1) ? (out + (size_t)(t - 1) * HDIM) : nullptr;
            gemmA<<<gridA, blk, 0, stream>>>(h, W_out, b_out, 1, outb, c2,
                                             W_r, b_gru + TH3, mhf);
            gemmB<<<gridB, blk, 0, stream>>>(outb, W_k, b_gru, mhf, h);
        }
        gemmA<<<gridInit, blk, 0, stream>>>(h, W_out, b_out, 1, outb,
                                            out + (size_t)(TSTEPS - 1) * HDIM,
                                            nullptr, nullptr, nullptr);
    }
}

// Round 4
// 5366.917 us; speedup vs baseline: 2.1804x; 1.7026x over previous
//
#include <hip/hip_runtime.h>
#include <math.h>

#define HDIM 1024
#define BROWS 256
#define TSTEPS 64
#define TH3 3072
#define RSCALE 1024.0f
#define RINV   0.0009765625f   // 2^-10

typedef _Float16 half8 __attribute__((ext_vector_type(8)));
typedef float float4v __attribute__((ext_vector_type(4)));

__device__ __forceinline__ float sigmoidf_(float x) {
    return 1.0f / (1.0f + __expf(-x));
}

__device__ __forceinline__ float4v mfma16(half8 a, half8 b, float4v c) {
    return __builtin_amdgcn_mfma_f32_16x16x32_f16(a, b, c, 0, 0, 0);
}

// halfword index of element (m,k) in a [256][1024] plane stored in MFMA
// A-fragment order: [mtile][ktile][lane][slot], lane=(m&15)+16*((k&31)>>3),
// slot=k&7. A wave's (mtile,ktile) fragment is 1KB contiguous.
__device__ __forceinline__ int frag_idx(int m, int k) {
    return (((m >> 4) * 32 + (k >> 5)) * 64 + ((m & 15) + (((k & 31) >> 3) << 4))) * 8 + (k & 7);
}

__device__ __forceinline__ void split16(float v, _Float16* hp, _Float16* lp) {
    const _Float16 h = (_Float16)v;
    *hp = h;
    *lp = (_Float16)((v - (float)h) * RSCALE);
}

// Write-through 2-byte store: sc0 sc1 -> bypasses L1/L2 to the device
// coherence point. L2 never holds dirty shared lines, so the grid barrier
// needs no writeback walk.
__device__ __forceinline__ void st_h16(_Float16* p, _Float16 v) {
    const unsigned u = (unsigned)__builtin_bit_cast(unsigned short, v);
    asm volatile("global_store_short %0, %1, off sc0 sc1"
                 :: "v"(p), "v"(u) : "memory");
}

// ---------------------------------------------------------------------------
// Split grid barrier (256 blocks = 8 groups x 32):
//   vmcnt(0) -> __syncthreads -> acquire fence (inv) -> arrive -> spin.
// R3 result: this ordering is stable (no 100ms outliers). Kept frozen.
// ---------------------------------------------------------------------------
__device__ __forceinline__ void gbar_arrive(unsigned* bar, unsigned gen) {
    asm volatile("s_waitcnt vmcnt(0)" ::: "memory");
    __syncthreads();
    __builtin_amdgcn_fence(__ATOMIC_ACQUIRE, "agent");   // inv, pre-spin
    if (threadIdx.x == 0) {
        unsigned* gc = bar + ((blockIdx.x & 7) << 5);   // 128B-separated group counters
        unsigned* rc = bar + 256;                       // root counter (own line)
        const unsigned old = __hip_atomic_fetch_add(gc, 1u, __ATOMIC_RELAXED,
                                                    __HIP_MEMORY_SCOPE_AGENT);
        if (old + 1u == gen * 32u)
            __hip_atomic_fetch_add(rc, 1u, __ATOMIC_RELAXED,
                                   __HIP_MEMORY_SCOPE_AGENT);
    }
}

__device__ __forceinline__ void gbar_wait(unsigned* bar, unsigned gen) {
    if (threadIdx.x == 0) {
        unsigned* rc = bar + 256;
        while (__hip_atomic_load(rc, __ATOMIC_RELAXED,
                                 __HIP_MEMORY_SCOPE_AGENT) < gen * 8u)
            __builtin_amdgcn_s_sleep(1);
    }
    __syncthreads();
}

__device__ __forceinline__ void gbar(unsigned* bar, unsigned gen) {
    gbar_arrive(bar, gen);
    gbar_wait(bar, gen);
}

// ---------------------------------------------------------------------------
// 3-pass split-fp16 GEMM panel, register double-buffered (chunk = 2 k-tiles,
// 8 lane-loads in flight), with PER-BLOCK K-ROTATION (rot in [0,16)):
// chunk traversal order is (c + rot) & 15. MFMA accumulation is
// order-independent, so each CU walks the shared activation planes starting
// at a different place -> the 32 CUs of an XCD demand ~16 distinct line
// regions at any instant instead of the same line simultaneously.
// (R2/R3 lesson: correlated burst misses across CUs are NOT merged by the
//  TCC -> 7.4x duplicate EA fetches, FETCH 0.67GB -> 7.6GB. De-correlating
//  the streams lets the leading CU fill a line and the rest hit it.)
// All rA indices are compile-time (full unroll) so the array stays in VGPRs.
// ---------------------------------------------------------------------------
__device__ __forceinline__ void gemm_panel(
    const half8* __restrict__ AH, const half8* __restrict__ AL,
    const _Float16* __restrict__ WH, const _Float16* __restrict__ WL,
    int mt0, int mt1, int lane, int rot,
    float4v& aH0, float4v& aXa0, float4v& aXb0,
    float4v& aH1, float4v& aXa1, float4v& aXb1)
{
    half8 rA[2][2][4];
    const int base0 = mt0 * 32 * 64 + lane;
    const int base1 = mt1 * 32 * 64 + lane;
    const int lofs = lane * 8;
#pragma unroll
    for (int kk = 0; kk < 2; ++kk) {
        const int kt = (rot & 15) * 2 + kk;          // chunk c=0
        rA[0][kk][0] = AH[base0 + kt * 64];
        rA[0][kk][1] = AL[base0 + kt * 64];
        rA[0][kk][2] = AH[base1 + kt * 64];
        rA[0][kk][3] = AL[base1 + kt * 64];
    }
#pragma unroll
    for (int c = 0; c < 16; ++c) {
        if (c < 15) {
#pragma unroll
            for (int kk = 0; kk < 2; ++kk) {
                const int kt = (((c + 1) + rot) & 15) * 2 + kk;
                rA[(c + 1) & 1][kk][0] = AH[base0 + kt * 64];
                rA[(c + 1) & 1][kk][1] = AL[base0 + kt * 64];
                rA[(c + 1) & 1][kk][2] = AH[base1 + kt * 64];
                rA[(c + 1) & 1][kk][3] = AL[base1 + kt * 64];
            }
        }
#pragma unroll
        for (int kk = 0; kk < 2; ++kk) {
            const int kt = ((c + rot) & 15) * 2 + kk;
            const half8 bh = *(const half8*)&WH[kt * 512 + lofs];
            const half8 bl = *(const half8*)&WL[kt * 512 + lofs];
            const half8 a0h = rA[c & 1][kk][0];
            const half8 a0l = rA[c & 1][kk][1];
            const half8 a1h = rA[c & 1][kk][2];
            const half8 a1l = rA[c & 1][kk][3];
            aH0  = mfma16(a0h, bh, aH0);
            aXa0 = mfma16(a0l, bh, aXa0);
            aXb0 = mfma16(a0h, bl, aXb0);
            aH1  = mfma16(a1h, bh, aH1);
            aXa1 = mfma16(a1l, bh, aXa1);
            aXb1 = mfma16(a1h, bl, aXb1);
        }
    }
}

// ===========================================================================
// Persistent cooperative kernel: 256 blocks x 512 threads (8 waves, 2/SIMD).
// LDS 140KB: WAh/WAl = phase-A panel [4 cols W_out | 12 W_r gate cols of
//            THIS block] as split-fp16 B-fragments;
//            WBh/WBl = 12 interleaved gate cols of W_k; mhs = [256][12] fp32.
// Activations in global as split-fp16 A-fragment planes (hH/hL, oH/oL),
// written through (sc0 sc1); mh never leaves the block (LDS); h state kept
// in registers by the gate lanes. Grid barrier frozen from R3; k-rotated,
// register-pipelined k-loops for de-correlated memory-level parallelism.
// ===========================================================================
__global__ __launch_bounds__(512, 2) void decoder_mfma(
    const float* __restrict__ x,
    const float* __restrict__ W_fs, const float* __restrict__ b_fs,
    const float* __restrict__ W_out, const float* __restrict__ b_out,
    const float* __restrict__ W_k,  const float* __restrict__ W_r,
    const float* __restrict__ b_gru,
    float* __restrict__ dout,
    _Float16* __restrict__ hH, _Float16* __restrict__ hL,
    _Float16* __restrict__ oH, _Float16* __restrict__ oL,
    unsigned* __restrict__ bar)
{
    extern __shared__ _Float16 ldsh[];
    _Float16* WAh = ldsh;              // 16384 halves = 32KB
    _Float16* WAl = ldsh + 16384;
    _Float16* WBh = ldsh + 32768;
    _Float16* WBl = ldsh + 49152;
    float*    mhs = (float*)(ldsh + 65536);   // [256][12] fp32 = 12KB

    const int b    = blockIdx.x;
    const int tid  = threadIdx.x;
    const int wv   = tid >> 6;         // wave 0..7
    const int lane = tid & 63;
    const int nn   = lane & 15;        // fragment n / C col
    const int kq   = lane >> 4;        // fragment k-quad / C row-quad
    // per-block k-rotation: blocks land round-robin on XCDs (XCD = b&7),
    // so (b>>3) enumerates same-XCD peers; &15 gives 16 distinct phases.
    const int rot  = (b >> 3) & 15;

    // ---------- one-time: pack weight panels into LDS fragment order -------
    // phase-A panel col n: n<4 -> W_out col 4b+n
    //                      n>=4: q=n-4, jj=q/3, ch=q%3 -> W_r col ch*1024+4b+jj
    for (int idx = tid; idx < 16384; idx += 512) {
        const int k = idx >> 4, n = idx & 15;
        float w;
        if (n < 4) {
            w = W_out[(size_t)k * HDIM + 4 * b + n];
        } else {
            const int q = n - 4, jj = q / 3, ch = q - 3 * jj;
            w = W_r[(size_t)k * TH3 + ch * 1024 + 4 * b + jj];
        }
        const int hw = ((k >> 5) * 64 + n + (((k & 31) >> 3) << 4)) * 8 + (k & 7);
        split16(w, &WAh[hw], &WAl[hw]);
    }
    for (int idx = tid; idx < 16384; idx += 512) {
        const int k = idx >> 4, n = idx & 15;
        float w = 0.0f;
        if (n < 12) {
            const int jj = n / 3, ch = n - 3 * jj;
            w = W_k[(size_t)k * TH3 + ch * 1024 + 4 * b + jj];
        }
        const int hw = ((k >> 5) * 64 + n + (((k & 31) >> 3) << 4)) * 8 + (k & 7);
        split16(w, &WBh[hw], &WBl[hw]);
    }

    // ---------- per-lane biases ----------
    float bA;
    if (nn < 4) {
        bA = b_out[4 * b + nn];
    } else {
        const int q = nn - 4, jj = q / 3, ch = q - 3 * jj;
        bA = b_gru[TH3 + ch * 1024 + 4 * b + jj];   // recurrent bias b_gru[1]
    }
    float bB = 0.0f;                                 // phase-B col bias (b_gru[0])
    if (nn < 12) {
        const int jj = nn / 3, ch = nn - 3 * jj;
        bB = b_gru[ch * 1024 + 4 * b + jj];
    }

    // ---------- phase 0: h0 = tanh(x @ W_fs + b_fs), 4 cols/block ----------
    {
        const int row = tid & 255;
        const int c = 4 * b + ((tid >> 8) << 1);     // 2 cols per thread
        float a0 = 0.0f, a1 = 0.0f;
        const float* xr = x + (size_t)row * HDIM;
        for (int k = 0; k < HDIM; k += 4) {
            const float4 xv = *(const float4*)(xr + k);
#pragma unroll
            for (int kk = 0; kk < 4; ++kk) {
                const float2 wv2 = *(const float2*)(W_fs + (size_t)(k + kk) * HDIM + c);
                const float av = (&xv.x)[kk];
                a0 = fmaf(av, wv2.x, a0);
                a1 = fmaf(av, wv2.y, a1);
            }
        }
        const float h0 = tanhf(a0 + b_fs[c]);
        const float h1 = tanhf(a1 + b_fs[c + 1]);
        _Float16 hi, lo;
        split16(h0, &hi, &lo);
        st_h16(&hH[frag_idx(row, c)], hi);
        st_h16(&hL[frag_idx(row, c)], lo);
        split16(h1, &hi, &lo);
        st_h16(&hH[frag_idx(row, c + 1)], hi);
        st_h16(&hL[frag_idx(row, c + 1)], lo);
    }
    unsigned gen = 0;
    gbar(bar, ++gen);

    const int mt0 = 2 * wv, mt1 = 2 * wv + 1;        // this wave's m-tiles
    float hreg[2][4];                                // gate lanes' fp32 h state

    // ---------- recurrence ----------
    for (int t = 0; ; ++t) {
        // ===== phase A: [out(4) | mh(12)] = h @ [W_out sel | W_r sel] =====
        {
            float4v aH0 = {0.f,0.f,0.f,0.f}, aXa0 = {0.f,0.f,0.f,0.f}, aXb0 = {0.f,0.f,0.f,0.f};
            float4v aH1 = {0.f,0.f,0.f,0.f}, aXa1 = {0.f,0.f,0.f,0.f}, aXb1 = {0.f,0.f,0.f,0.f};
            gemm_panel((const half8*)hH, (const half8*)hL, WAh, WAl,
                       mt0, mt1, lane, rot, aH0, aXa0, aXb0, aH1, aXa1, aXb1);
#pragma unroll
            for (int m = 0; m < 2; ++m) {
                const int mt = (m == 0) ? mt0 : mt1;
#pragma unroll
                for (int r = 0; r < 4; ++r) {
                    const int row = mt * 16 + kq * 4 + r;
                    float v = ((m == 0) ? aH0[r] + (aXa0[r] + aXb0[r]) * RINV
                                        : aH1[r] + (aXa1[r] + aXb1[r]) * RINV) + bA;
                    if (nn < 4) {
                        v = fmaxf(v, 0.0f);
                        if (t < TSTEPS) {
                            _Float16 hi, lo;
                            split16(v, &hi, &lo);
                            const int fi = frag_idx(row, 4 * b + nn);
                            st_h16(&oH[fi], hi);
                            st_h16(&oL[fi], lo);
                        }
                    } else if (t < TSTEPS) {
                        mhs[row * 12 + (nn - 4)] = v;   // mh stays in LDS
                    }
                }
            }
            if (t == TSTEPS) {
                // final out column -> dout col T-1, then done
                if (nn < 4) {
#pragma unroll
                    for (int m = 0; m < 2; ++m) {
                        const int mt = (m == 0) ? mt0 : mt1;
#pragma unroll
                        for (int r = 0; r < 4; ++r) {
                            const int row = mt * 16 + kq * 4 + r;
                            const float v = fmaxf(((m == 0) ? aH0[r] + (aXa0[r] + aXb0[r]) * RINV
                                                            : aH1[r] + (aXa1[r] + aXb1[r]) * RINV) + bA, 0.0f);
                            __builtin_nontemporal_store(
                                v, &dout[(size_t)row * (TSTEPS * HDIM) +
                                         (size_t)(TSTEPS - 1) * HDIM + 4 * b + nn]);
                        }
                    }
                }
                break;
            }
            gbar_arrive(bar, ++gen);
            // private dout stores hide under the barrier spin
            if (nn < 4 && t >= 1) {
#pragma unroll
                for (int m = 0; m < 2; ++m) {
                    const int mt = (m == 0) ? mt0 : mt1;
#pragma unroll
                    for (int r = 0; r < 4; ++r) {
                        const int row = mt * 16 + kq * 4 + r;
                        const float v = fmaxf(((m == 0) ? aH0[r] + (aXa0[r] + aXb0[r]) * RINV
                                                        : aH1[r] + (aXa1[r] + aXb1[r]) * RINV) + bA, 0.0f);
                        __builtin_nontemporal_store(
                            v, &dout[(size_t)row * (TSTEPS * HDIM) +
                                     (size_t)(t - 1) * HDIM + 4 * b + nn]);
                    }
                }
            }
            gbar_wait(bar, gen);
        }

        // ===== phase B: mx = out @ W_k + fused GRU gates -> h planes =====
        {
            float4v aH0 = {0.f,0.f,0.f,0.f}, aXa0 = {0.f,0.f,0.f,0.f}, aXb0 = {0.f,0.f,0.f,0.f};
            float4v aH1 = {0.f,0.f,0.f,0.f}, aXa1 = {0.f,0.f,0.f,0.f}, aXb1 = {0.f,0.f,0.f,0.f};
            gemm_panel((const half8*)oH, (const half8*)oL, WBh, WBl,
                       mt0, mt1, lane, rot, aH0, aXa0, aXb0, aH1, aXa1, aXb1);
            // per-lane mx values (col nn), bias folded
            float vals[2][4], v1[2][4], v2[2][4];
#pragma unroll
            for (int r = 0; r < 4; ++r) {
                vals[0][r] = aH0[r] + (aXa0[r] + aXb0[r]) * RINV + bB;
                vals[1][r] = aH1[r] + (aXa1[r] + aXb1[r]) * RINV + bB;
            }
            // gather r-gate (col+1) and h-gate (col+2) values to z-lanes
#pragma unroll
            for (int m = 0; m < 2; ++m)
#pragma unroll
                for (int r = 0; r < 4; ++r) {
                    v1[m][r] = __shfl(vals[m][r], (lane + 1) & 63);
                    v2[m][r] = __shfl(vals[m][r], (lane + 2) & 63);
                }
            if (nn < 12 && (nn % 3) == 0) {
                const int jj = nn / 3;
                const int j = 4 * b + jj;
                if (t == 0) {
#pragma unroll
                    for (int m = 0; m < 2; ++m)
#pragma unroll
                        for (int r = 0; r < 4; ++r) {
                            const int mt = (m == 0) ? mt0 : mt1;
                            const int row = mt * 16 + kq * 4 + r;
                            const int fi = frag_idx(row, j);
                            hreg[m][r] = (float)hH[fi] + (float)hL[fi] * RINV;
                        }
                }
#pragma unroll
                for (int m = 0; m < 2; ++m) {
                    const int mt = (m == 0) ? mt0 : mt1;
#pragma unroll
                    for (int r = 0; r < 4; ++r) {
                        const int row = mt * 16 + kq * 4 + r;
                        const float* mrow = &mhs[row * 12 + 3 * jj];
                        const float z    = sigmoidf_(vals[m][r] + mrow[0]);
                        const float rg   = sigmoidf_(v1[m][r] + mrow[1]);
                        const float cand = tanhf(v2[m][r] + rg * mrow[2]);
                        const float hn = z * hreg[m][r] + (1.0f - z) * cand;
                        hreg[m][r] = hn;
                        const int fi = frag_idx(row, j);
                        _Float16 hi, lo;
                        split16(hn, &hi, &lo);
                        st_h16(&hH[fi], hi);
                        st_h16(&hL[fi], lo);
                    }
                }
            }
            gbar(bar, ++gen);
        }
    }
}

// ===========================================================================
// Fallback path (round-2 kernels) — used only if cooperative launch fails.
// ===========================================================================
__global__ __launch_bounds__(128) void gemmA(
    const float* __restrict__ A,
    const float* __restrict__ W0, const float* __restrict__ b0, int act0,
    float* __restrict__ C0, float* __restrict__ C2,
    const float* __restrict__ W1, const float* __restrict__ b1,
    float* __restrict__ C1)
{
    __shared__ __align__(16) float Ass[32][36];
    __shared__ __align__(16) float Ws[32][68];
    const int tid = threadIdx.x;
    const int bx = blockIdx.x, by = blockIdx.y;
    const int r0 = by * 32;
    const bool reg0 = (bx < 16);
    const int c0 = reg0 ? bx * 64 : (bx - 16) * 64;
    const float* __restrict__ W = reg0 ? W0 : W1;
    const int ldw = reg0 ? 1024 : 3072;
    const int arow = tid >> 2;
    const int ak   = (tid & 3) << 2;
    const int wrow = tid >> 4;
    const int wcol = (tid & 15) << 2;
    const int ty = tid >> 4;
    const int tx = tid & 15;
    float acc[4][4] = {};
    const float* Ap = A + (size_t)(r0 + arow) * 1024 + ak;
    const float* Wp = W + (size_t)wrow * ldw + c0 + wcol;
    for (int k0 = 0; k0 < 1024; k0 += 32) {
        const float4 a0 = *(const float4*)(Ap + k0);
        const float4 a1 = *(const float4*)(Ap + k0 + 16);
        const float4 w0 = *(const float4*)(Wp + (size_t)k0 * ldw);
        const float4 w1 = *(const float4*)(Wp + (size_t)(k0 + 8) * ldw);
        const float4 w2 = *(const float4*)(Wp + (size_t)(k0 + 16) * ldw);
        const float4 w3 = *(const float4*)(Wp + (size_t)(k0 + 24) * ldw);
        __syncthreads();
        Ass[ak + 0][arow] = a0.x; Ass[ak + 1][arow] = a0.y;
        Ass[ak + 2][arow] = a0.z; Ass[ak + 3][arow] = a0.w;
        Ass[ak + 16][arow] = a1.x; Ass[ak + 17][arow] = a1.y;
        Ass[ak + 18][arow] = a1.z; Ass[ak + 19][arow] = a1.w;
        *(float4*)&Ws[wrow][wcol]      = w0;
        *(float4*)&Ws[wrow + 8][wcol]  = w1;
        *(float4*)&Ws[wrow + 16][wcol] = w2;
        *(float4*)&Ws[wrow + 24][wcol] = w3;
        __syncthreads();
#pragma unroll
        for (int kk = 0; kk < 32; ++kk) {
            const float4 a4 = *(const float4*)&Ass[kk][ty << 2];
            const float4 w4 = *(const float4*)&Ws[kk][tx << 2];
            const float a[4] = {a4.x, a4.y, a4.z, a4.w};
            const float w[4] = {w4.x, w4.y, w4.z, w4.w};
#pragma unroll
            for (int i = 0; i < 4; ++i)
#pragma unroll
                for (int j = 0; j < 4; ++j)
                    acc[i][j] = fmaf(a[i], w[j], acc[i][j]);
        }
    }
    const float* bias = reg0 ? b0 : b1;
    const float4 bv = *(const float4*)(bias + c0 + (tx << 2));
    const float bb[4] = {bv.x, bv.y, bv.z, bv.w};
#pragma unroll
    for (int i = 0; i < 4; ++i) {
        const int row = r0 + (ty << 2) + i;
        float v[4];
#pragma unroll
        for (int j = 0; j < 4; ++j) {
            float tv = acc[i][j] + bb[j];
            if (reg0) { tv = (act0 == 1) ? fmaxf(tv, 0.0f) : tanhf(tv); }
            v[j] = tv;
        }
        const float4 o = make_float4(v[0], v[1], v[2], v[3]);
        if (reg0) {
            *(float4*)(C0 + (size_t)row * 1024 + c0 + (tx << 2)) = o;
            if (C2)
                *(float4*)(C2 + (size_t)row * (TSTEPS * HDIM) + c0 + (tx << 2)) = o;
        } else {
            *(float4*)(C1 + (size_t)row * TH3 + c0 + (tx << 2)) = o;
        }
    }
}

__global__ __launch_bounds__(128) void gemmB(
    const float* __restrict__ A,
    const float* __restrict__ Wk,
    const float* __restrict__ bg,
    const float* __restrict__ mh,
    float* __restrict__ h)
{
    __shared__ __align__(16) float Ass[32][36];
    __shared__ __align__(16) float Ws[3][32][20];
    const int tid = threadIdx.x;
    const int j0 = blockIdx.x * 16;
    const int r0 = blockIdx.y * 32;
    const int arow = tid >> 2;
    const int ak   = (tid & 3) << 2;
    const int wr   = tid >> 2;
    const int wc   = (tid & 3) << 2;
    const int ty = tid >> 4;
    const int tx = tid & 15;
    float acc[3][4] = {};
    const float* Ap = A + (size_t)(r0 + arow) * 1024 + ak;
    const float* Wp = Wk + (size_t)wr * TH3 + j0 + wc;
    for (int k0 = 0; k0 < 1024; k0 += 32) {
        const float4 a0 = *(const float4*)(Ap + k0);
        const float4 a1 = *(const float4*)(Ap + k0 + 16);
        float4 wv[3];
#pragma unroll
        for (int c = 0; c < 3; ++c)
            wv[c] = *(const float4*)(Wp + (size_t)k0 * TH3 + c * 1024);
        __syncthreads();
        Ass[ak + 0][arow] = a0.x; Ass[ak + 1][arow] = a0.y;
        Ass[ak + 2][arow] = a0.z; Ass[ak + 3][arow] = a0.w;
        Ass[ak + 16][arow] = a1.x; Ass[ak + 17][arow] = a1.y;
        Ass[ak + 18][arow] = a1.z; Ass[ak + 19][arow] = a1.w;
#pragma unroll
        for (int c = 0; c < 3; ++c)
            *(float4*)&Ws[c][wr][wc] = wv[c];
        __syncthreads();
#pragma unroll
        for (int kk = 0; kk < 32; ++kk) {
            const float4 a4 = *(const float4*)&Ass[kk][ty << 2];
            const float a[4] = {a4.x, a4.y, a4.z, a4.w};
            const float wz = Ws[0][kk][tx];
            const float wr_ = Ws[1][kk][tx];
            const float wh = Ws[2][kk][tx];
#pragma unroll
            for (int i = 0; i < 4; ++i) {
                acc[0][i] = fmaf(a[i], wz, acc[0][i]);
                acc[1][i] = fmaf(a[i], wr_, acc[1][i]);
                acc[2][i] = fmaf(a[i], wh, acc[2][i]);
            }
        }
    }
    const int j = j0 + tx;
    const float bz = bg[j];
    const float br = bg[HDIM + j];
    const float bh = bg[2 * HDIM + j];
#pragma unroll
    for (int i = 0; i < 4; ++i) {
        const int row = r0 + (ty << 2) + i;
        const float* mhp = mh + (size_t)row * TH3;
        const float z  = sigmoidf_(acc[0][i] + bz + mhp[j]);
        const float rg = sigmoidf_(acc[1][i] + br + mhp[HDIM + j]);
        const float cand = tanhf(acc[2][i] + bh + rg * mhp[2 * HDIM + j]);
        const size_t hi = (size_t)row * HDIM + j;
        const float ho = h[hi];
        h[hi] = z * ho + (1.0f - z) * cand;
    }
}

extern "C" void kernel_launch(void* const* d_in, const int* in_sizes, int n_in,
                              void* d_out, int out_size, void* d_ws, size_t ws_size,
                              hipStream_t stream) {
    const float* x     = (const float*)d_in[0];
    const float* W_fs  = (const float*)d_in[1];
    const float* b_fs  = (const float*)d_in[2];
    const float* W_out = (const float*)d_in[3];
    const float* b_out = (const float*)d_in[4];
    const float* W_k   = (const float*)d_in[5];
    const float* W_r   = (const float*)d_in[6];
    const float* b_gru = (const float*)d_in[7];
    float* out = (float*)d_out;            // [B, T, H]

    char* ws = (char*)d_ws;
    _Float16* hH = (_Float16*)(ws);                  // 512KB each plane
    _Float16* hL = (_Float16*)(ws + 512 * 1024);
    _Float16* oH = (_Float16*)(ws + 1024 * 1024);
    _Float16* oL = (_Float16*)(ws + 1536 * 1024);
    unsigned* bar = (unsigned*)(ws + 2048 * 1024);   // barrier counters (2KB)

    // barrier counters must start at 0 every launch (graph-capture safe)
    hipMemsetAsync(bar, 0, 2048, stream);

    void* args[] = {
        (void*)&x, (void*)&W_fs, (void*)&b_fs, (void*)&W_out, (void*)&b_out,
        (void*)&W_k, (void*)&W_r, (void*)&b_gru, (void*)&out,
        (void*)&hH, (void*)&hL, (void*)&oH, (void*)&oL, (void*)&bar
    };
    const size_t lds_bytes = 131072 + 12288;         // panels 128KB + mhs 12KB
    hipError_t err = hipLaunchCooperativeKernel(
        (const void*)decoder_mfma, dim3(256), dim3(512),
        args, lds_bytes, stream);

    if (err != hipSuccess) {
        // fallback: round-2 multi-launch fp32 path
        float* h    = (float*)d_ws;
        float* outb = h    + BROWS * HDIM;
        float* mhf  = outb + BROWS * HDIM;
        const dim3 blk(128);
        const dim3 gridInit(16, 8);
        const dim3 gridA(64, 8);
        const dim3 gridB(64, 8);
        gemmA<<<gridInit, blk, 0, stream>>>(x, W_fs, b_fs, 2, h, nullptr,
                                            nullptr, nullptr, nullptr);
        for (int t = 0; t < TSTEPS; ++t) {
            float* c2 = (t >= 1) ? (out + (size_t)(t - 1) * HDIM) : nullptr;
            gemmA<<<gridA, blk, 0, stream>>>(h, W_out, b_out, 1, outb, c2,
                                             W_r, b_gru + TH3, mhf);
            gemmB<<<gridB, blk, 0, stream>>>(outb, W_k, b_gru, mhf, h);
        }
        gemmA<<<gridInit, blk, 0, stream>>>(h, W_out, b_out, 1, outb,
                                            out + (size_t)(TSTEPS - 1) * HDIM,
                                            nullptr, nullptr, nullptr);
    }
}

// Round 5
// 3844.946 us; speedup vs baseline: 3.0435x; 1.3958x over previous
//
#include <hip/hip_runtime.h>
#include <math.h>

#define HDIM 1024
#define BROWS 256
#define TSTEPS 64
#define TH3 3072
#define RSCALE 1024.0f
#define RINV   0.0009765625f   // 2^-10

typedef _Float16 half8 __attribute__((ext_vector_type(8)));
typedef float float4v __attribute__((ext_vector_type(4)));

__device__ __forceinline__ float sigmoidf_(float x) {
    return 1.0f / (1.0f + __expf(-x));
}

__device__ __forceinline__ float4v mfma16(half8 a, half8 b, float4v c) {
    return __builtin_amdgcn_mfma_f32_16x16x32_f16(a, b, c, 0, 0, 0);
}

// halfword index of element (m,k) in a [256][1024] plane stored in MFMA
// A-fragment order: [mtile][ktile][lane][slot], lane=(m&15)+16*((k&31)>>3),
// slot=k&7. A wave's (mtile,ktile) fragment is 1KB contiguous.
__device__ __forceinline__ int frag_idx(int m, int k) {
    return (((m >> 4) * 32 + (k >> 5)) * 64 + ((m & 15) + (((k & 31) >> 3) << 4))) * 8 + (k & 7);
}

__device__ __forceinline__ void split16(float v, _Float16* hp, _Float16* lp) {
    const _Float16 h = (_Float16)v;
    *hp = h;
    *lp = (_Float16)((v - (float)h) * RSCALE);
}

// Write-through 2-byte store: sc0 sc1 -> bypasses L1/L2 to the device
// coherence point. L2 never holds dirty shared lines, so the grid barrier
// needs no writeback walk.
__device__ __forceinline__ void st_h16(_Float16* p, _Float16 v) {
    const unsigned u = (unsigned)__builtin_bit_cast(unsigned short, v);
    asm volatile("global_store_short %0, %1, off sc0 sc1"
                 :: "v"(p), "v"(u) : "memory");
}

// ---------------------------------------------------------------------------
// Split grid barrier (256 blocks = 8 groups x 32) with ASYMMETRIC CACHE INV.
// R1-R4 lesson: phase time (~37-42us) is invariant to load strategy -> the
// constant is the barrier machinery. Suspect: 32 per-block agent acquire
// fences per XCD each doing a full L2 invalidate, serializing at the TCC.
// Fix: every block invalidates only its own CU L1 (buffer_inv sc0, cheap,
// parallel); exactly ONE designated block per physical XCD (elected via
// HW_REG_XCC_ID + atomicMax) also invalidates the shared L2
// (buffer_inv sc0 sc1). Both complete (vmcnt) BEFORE arrive, so release
// implies every XCD's L2 and every CU's L1 are clean -- same coverage as
// 32 fences, 1/32 the L2-inv traffic. Write-through stores mean no L2 line
// is ever dirty, so inv (not wb) is sufficient.
// ---------------------------------------------------------------------------
__device__ __forceinline__ void gbar_arrive(unsigned* bar, unsigned gen, bool isdes) {
    asm volatile("s_waitcnt vmcnt(0)" ::: "memory");
    __syncthreads();
    if (threadIdx.x == 0) {
        if (isdes) {
            asm volatile("buffer_inv sc0 sc1\n\ts_waitcnt vmcnt(0)" ::: "memory");
        } else {
            asm volatile("buffer_inv sc0\n\ts_waitcnt vmcnt(0)" ::: "memory");
        }
        unsigned* gc = bar + ((blockIdx.x & 7) << 5);   // 128B-separated group counters
        unsigned* rc = bar + 256;                       // root counter (own line)
        const unsigned old = __hip_atomic_fetch_add(gc, 1u, __ATOMIC_RELAXED,
                                                    __HIP_MEMORY_SCOPE_AGENT);
        if (old + 1u == gen * 32u)
            __hip_atomic_fetch_add(rc, 1u, __ATOMIC_RELAXED,
                                   __HIP_MEMORY_SCOPE_AGENT);
    }
}

__device__ __forceinline__ void gbar_wait(unsigned* bar, unsigned gen) {
    if (threadIdx.x == 0) {
        unsigned* rc = bar + 256;
        while (__hip_atomic_load(rc, __ATOMIC_RELAXED,
                                 __HIP_MEMORY_SCOPE_AGENT) < gen * 8u)
            __builtin_amdgcn_s_sleep(1);
    }
    __syncthreads();
    // compiler-level barrier only; HW caches were inv'd pre-arrive
    asm volatile("" ::: "memory");
}

__device__ __forceinline__ void gbar(unsigned* bar, unsigned gen, bool isdes) {
    gbar_arrive(bar, gen, isdes);
    gbar_wait(bar, gen);
}

// Startup-only conservative barrier (full agent fence from every block).
__device__ __forceinline__ void gbar_full(unsigned* bar, unsigned gen) {
    asm volatile("s_waitcnt vmcnt(0)" ::: "memory");
    __syncthreads();
    __builtin_amdgcn_fence(__ATOMIC_ACQUIRE, "agent");
    if (threadIdx.x == 0) {
        unsigned* gc = bar + ((blockIdx.x & 7) << 5);
        unsigned* rc = bar + 256;
        const unsigned old = __hip_atomic_fetch_add(gc, 1u, __ATOMIC_RELAXED,
                                                    __HIP_MEMORY_SCOPE_AGENT);
        if (old + 1u == gen * 32u)
            __hip_atomic_fetch_add(rc, 1u, __ATOMIC_RELAXED,
                                   __HIP_MEMORY_SCOPE_AGENT);
    }
    gbar_wait(bar, gen);
}

// ---------------------------------------------------------------------------
// 3-pass split-fp16 GEMM panel, register double-buffered (chunk = 2 k-tiles,
// 8 lane-loads in flight), with PER-BLOCK K-ROTATION (rot in [0,16)):
// de-correlates same-XCD CUs' miss streams (R4: FETCH 7.6GB -> 4.5GB).
// All rA indices are compile-time (full unroll) so the array stays in VGPRs.
// ---------------------------------------------------------------------------
__device__ __forceinline__ void gemm_panel(
    const half8* __restrict__ AH, const half8* __restrict__ AL,
    const _Float16* __restrict__ WH, const _Float16* __restrict__ WL,
    int mt0, int mt1, int lane, int rot,
    float4v& aH0, float4v& aXa0, float4v& aXb0,
    float4v& aH1, float4v& aXa1, float4v& aXb1)
{
    half8 rA[2][2][4];
    const int base0 = mt0 * 32 * 64 + lane;
    const int base1 = mt1 * 32 * 64 + lane;
    const int lofs = lane * 8;
#pragma unroll
    for (int kk = 0; kk < 2; ++kk) {
        const int kt = (rot & 15) * 2 + kk;          // chunk c=0
        rA[0][kk][0] = AH[base0 + kt * 64];
        rA[0][kk][1] = AL[base0 + kt * 64];
        rA[0][kk][2] = AH[base1 + kt * 64];
        rA[0][kk][3] = AL[base1 + kt * 64];
    }
#pragma unroll
    for (int c = 0; c < 16; ++c) {
        if (c < 15) {
#pragma unroll
            for (int kk = 0; kk < 2; ++kk) {
                const int kt = (((c + 1) + rot) & 15) * 2 + kk;
                rA[(c + 1) & 1][kk][0] = AH[base0 + kt * 64];
                rA[(c + 1) & 1][kk][1] = AL[base0 + kt * 64];
                rA[(c + 1) & 1][kk][2] = AH[base1 + kt * 64];
                rA[(c + 1) & 1][kk][3] = AL[base1 + kt * 64];
            }
        }
#pragma unroll
        for (int kk = 0; kk < 2; ++kk) {
            const int kt = ((c + rot) & 15) * 2 + kk;
            const half8 bh = *(const half8*)&WH[kt * 512 + lofs];
            const half8 bl = *(const half8*)&WL[kt * 512 + lofs];
            const half8 a0h = rA[c & 1][kk][0];
            const half8 a0l = rA[c & 1][kk][1];
            const half8 a1h = rA[c & 1][kk][2];
            const half8 a1l = rA[c & 1][kk][3];
            aH0  = mfma16(a0h, bh, aH0);
            aXa0 = mfma16(a0l, bh, aXa0);
            aXb0 = mfma16(a0h, bl, aXb0);
            aH1  = mfma16(a1h, bh, aH1);
            aXa1 = mfma16(a1l, bh, aXa1);
            aXb1 = mfma16(a1h, bl, aXb1);
        }
    }
}

// ===========================================================================
// Persistent cooperative kernel: 256 blocks x 512 threads (8 waves, 2/SIMD).
// LDS 140KB: WAh/WAl = phase-A panel [4 cols W_out | 12 W_r gate cols of
//            THIS block] as split-fp16 B-fragments;
//            WBh/WBl = 12 interleaved gate cols of W_k; mhs = [256][12] fp32.
// Activations in global as split-fp16 A-fragment planes (hH/hL, oH/oL),
// written through (sc0 sc1); mh never leaves the block (LDS); h state kept
// in registers by the gate lanes. Asymmetric-inv grid barrier (1 L2 inv per
// XCD per barrier); k-rotated register-pipelined k-loops.
// ===========================================================================
__global__ __launch_bounds__(512, 2) void decoder_mfma(
    const float* __restrict__ x,
    const float* __restrict__ W_fs, const float* __restrict__ b_fs,
    const float* __restrict__ W_out, const float* __restrict__ b_out,
    const float* __restrict__ W_k,  const float* __restrict__ W_r,
    const float* __restrict__ b_gru,
    float* __restrict__ dout,
    _Float16* __restrict__ hH, _Float16* __restrict__ hL,
    _Float16* __restrict__ oH, _Float16* __restrict__ oL,
    unsigned* __restrict__ bar)
{
    extern __shared__ _Float16 ldsh[];
    _Float16* WAh = ldsh;              // 16384 halves = 32KB
    _Float16* WAl = ldsh + 16384;
    _Float16* WBh = ldsh + 32768;
    _Float16* WBl = ldsh + 49152;
    float*    mhs = (float*)(ldsh + 65536);   // [256][12] fp32 = 12KB

    const int b    = blockIdx.x;
    const int tid  = threadIdx.x;
    const int wv   = tid >> 6;         // wave 0..7
    const int lane = tid & 63;
    const int nn   = lane & 15;        // fragment n / C col
    const int kq   = lane >> 4;        // fragment k-quad / C row-quad
    // per-block k-rotation phase among same-XCD peers (perf-only heuristic)
    const int rot  = (b >> 3) & 15;

    // physical XCD id (0..7) -- correctness-critical for the L2-inv election
    unsigned xcd;
    asm("s_getreg_b32 %0, hwreg(HW_REG_XCC_ID)" : "=s"(xcd));
    xcd &= 7u;
    // election: max blockIdx on this XCD becomes the designated L2 invalidator
    if (tid == 0)
        __hip_atomic_fetch_max(&bar[288 + xcd], (unsigned)b, __ATOMIC_RELAXED,
                               __HIP_MEMORY_SCOPE_AGENT);

    // ---------- one-time: pack weight panels into LDS fragment order -------
    // phase-A panel col n: n<4 -> W_out col 4b+n
    //                      n>=4: q=n-4, jj=q/3, ch=q%3 -> W_r col ch*1024+4b+jj
    for (int idx = tid; idx < 16384; idx += 512) {
        const int k = idx >> 4, n = idx & 15;
        float w;
        if (n < 4) {
            w = W_out[(size_t)k * HDIM + 4 * b + n];
        } else {
            const int q = n - 4, jj = q / 3, ch = q - 3 * jj;
            w = W_r[(size_t)k * TH3 + ch * 1024 + 4 * b + jj];
        }
        const int hw = ((k >> 5) * 64 + n + (((k & 31) >> 3) << 4)) * 8 + (k & 7);
        split16(w, &WAh[hw], &WAl[hw]);
    }
    for (int idx = tid; idx < 16384; idx += 512) {
        const int k = idx >> 4, n = idx & 15;
        float w = 0.0f;
        if (n < 12) {
            const int jj = n / 3, ch = n - 3 * jj;
            w = W_k[(size_t)k * TH3 + ch * 1024 + 4 * b + jj];
        }
        const int hw = ((k >> 5) * 64 + n + (((k & 31) >> 3) << 4)) * 8 + (k & 7);
        split16(w, &WBh[hw], &WBl[hw]);
    }

    // ---------- per-lane biases ----------
    float bA;
    if (nn < 4) {
        bA = b_out[4 * b + nn];
    } else {
        const int q = nn - 4, jj = q / 3, ch = q - 3 * jj;
        bA = b_gru[TH3 + ch * 1024 + 4 * b + jj];   // recurrent bias b_gru[1]
    }
    float bB = 0.0f;                                 // phase-B col bias (b_gru[0])
    if (nn < 12) {
        const int jj = nn / 3, ch = nn - 3 * jj;
        bB = b_gru[ch * 1024 + 4 * b + jj];
    }

    // ---------- phase 0: h0 = tanh(x @ W_fs + b_fs), 4 cols/block ----------
    {
        const int row = tid & 255;
        const int c = 4 * b + ((tid >> 8) << 1);     // 2 cols per thread
        float a0 = 0.0f, a1 = 0.0f;
        const float* xr = x + (size_t)row * HDIM;
        for (int k = 0; k < HDIM; k += 4) {
            const float4 xv = *(const float4*)(xr + k);
#pragma unroll
            for (int kk = 0; kk < 4; ++kk) {
                const float2 wv2 = *(const float2*)(W_fs + (size_t)(k + kk) * HDIM + c);
                const float av = (&xv.x)[kk];
                a0 = fmaf(av, wv2.x, a0);
                a1 = fmaf(av, wv2.y, a1);
            }
        }
        const float h0 = tanhf(a0 + b_fs[c]);
        const float h1 = tanhf(a1 + b_fs[c + 1]);
        _Float16 hi, lo;
        split16(h0, &hi, &lo);
        st_h16(&hH[frag_idx(row, c)], hi);
        st_h16(&hL[frag_idx(row, c)], lo);
        split16(h1, &hi, &lo);
        st_h16(&hH[frag_idx(row, c + 1)], hi);
        st_h16(&hL[frag_idx(row, c + 1)], lo);
    }
    unsigned gen = 0;
    gbar_full(bar, ++gen);          // startup barrier: conservative full fence

    // read election result (agent-scope load; post-full-fence so no staleness)
    const unsigned desblk = __hip_atomic_load(&bar[288 + xcd], __ATOMIC_RELAXED,
                                              __HIP_MEMORY_SCOPE_AGENT);
    const bool isdes = (desblk == (unsigned)b);

    const int mt0 = 2 * wv, mt1 = 2 * wv + 1;        // this wave's m-tiles
    float hreg[2][4];                                // gate lanes' fp32 h state

    // ---------- recurrence ----------
    for (int t = 0; ; ++t) {
        // ===== phase A: [out(4) | mh(12)] = h @ [W_out sel | W_r sel] =====
        {
            float4v aH0 = {0.f,0.f,0.f,0.f}, aXa0 = {0.f,0.f,0.f,0.f}, aXb0 = {0.f,0.f,0.f,0.f};
            float4v aH1 = {0.f,0.f,0.f,0.f}, aXa1 = {0.f,0.f,0.f,0.f}, aXb1 = {0.f,0.f,0.f,0.f};
            gemm_panel((const half8*)hH, (const half8*)hL, WAh, WAl,
                       mt0, mt1, lane, rot, aH0, aXa0, aXb0, aH1, aXa1, aXb1);
#pragma unroll
            for (int m = 0; m < 2; ++m) {
                const int mt = (m == 0) ? mt0 : mt1;
#pragma unroll
                for (int r = 0; r < 4; ++r) {
                    const int row = mt * 16 + kq * 4 + r;
                    float v = ((m == 0) ? aH0[r] + (aXa0[r] + aXb0[r]) * RINV
                                        : aH1[r] + (aXa1[r] + aXb1[r]) * RINV) + bA;
                    if (nn < 4) {
                        v = fmaxf(v, 0.0f);
                        if (t < TSTEPS) {
                            _Float16 hi, lo;
                            split16(v, &hi, &lo);
                            const int fi = frag_idx(row, 4 * b + nn);
                            st_h16(&oH[fi], hi);
                            st_h16(&oL[fi], lo);
                        }
                    } else if (t < TSTEPS) {
                        mhs[row * 12 + (nn - 4)] = v;   // mh stays in LDS
                    }
                }
            }
            if (t == TSTEPS) {
                // final out column -> dout col T-1, then done
                if (nn < 4) {
#pragma unroll
                    for (int m = 0; m < 2; ++m) {
                        const int mt = (m == 0) ? mt0 : mt1;
#pragma unroll
                        for (int r = 0; r < 4; ++r) {
                            const int row = mt * 16 + kq * 4 + r;
                            const float v = fmaxf(((m == 0) ? aH0[r] + (aXa0[r] + aXb0[r]) * RINV
                                                            : aH1[r] + (aXa1[r] + aXb1[r]) * RINV) + bA, 0.0f);
                            __builtin_nontemporal_store(
                                v, &dout[(size_t)row * (TSTEPS * HDIM) +
                                         (size_t)(TSTEPS - 1) * HDIM + 4 * b + nn]);
                        }
                    }
                }
                break;
            }
            gbar_arrive(bar, ++gen, isdes);
            // private dout stores hide under the barrier spin
            if (nn < 4 && t >= 1) {
#pragma unroll
                for (int m = 0; m < 2; ++m) {
                    const int mt = (m == 0) ? mt0 : mt1;
#pragma unroll
                    for (int r = 0; r < 4; ++r) {
                        const int row = mt * 16 + kq * 4 + r;
                        const float v = fmaxf(((m == 0) ? aH0[r] + (aXa0[r] + aXb0[r]) * RINV
                                                        : aH1[r] + (aXa1[r] + aXb1[r]) * RINV) + bA, 0.0f);
                        __builtin_nontemporal_store(
                            v, &dout[(size_t)row * (TSTEPS * HDIM) +
                                     (size_t)(t - 1) * HDIM + 4 * b + nn]);
                    }
                }
            }
            gbar_wait(bar, gen);
        }

        // ===== phase B: mx = out @ W_k + fused GRU gates -> h planes =====
        {
            float4v aH0 = {0.f,0.f,0.f,0.f}, aXa0 = {0.f,0.f,0.f,0.f}, aXb0 = {0.f,0.f,0.f,0.f};
            float4v aH1 = {0.f,0.f,0.f,0.f}, aXa1 = {0.f,0.f,0.f,0.f}, aXb1 = {0.f,0.f,0.f,0.f};
            gemm_panel((const half8*)oH, (const half8*)oL, WBh, WBl,
                       mt0, mt1, lane, rot, aH0, aXa0, aXb0, aH1, aXa1, aXb1);
            // per-lane mx values (col nn), bias folded
            float vals[2][4], v1[2][4], v2[2][4];
#pragma unroll
            for (int r = 0; r < 4; ++r) {
                vals[0][r] = aH0[r] + (aXa0[r] + aXb0[r]) * RINV + bB;
                vals[1][r] = aH1[r] + (aXa1[r] + aXb1[r]) * RINV + bB;
            }
            // gather r-gate (col+1) and h-gate (col+2) values to z-lanes
#pragma unroll
            for (int m = 0; m < 2; ++m)
#pragma unroll
                for (int r = 0; r < 4; ++r) {
                    v1[m][r] = __shfl(vals[m][r], (lane + 1) & 63);
                    v2[m][r] = __shfl(vals[m][r], (lane + 2) & 63);
                }
            if (nn < 12 && (nn % 3) == 0) {
                const int jj = nn / 3;
                const int j = 4 * b + jj;
                if (t == 0) {
#pragma unroll
                    for (int m = 0; m < 2; ++m)
#pragma unroll
                        for (int r = 0; r < 4; ++r) {
                            const int mt = (m == 0) ? mt0 : mt1;
                            const int row = mt * 16 + kq * 4 + r;
                            const int fi = frag_idx(row, j);
                            hreg[m][r] = (float)hH[fi] + (float)hL[fi] * RINV;
                        }
                }
#pragma unroll
                for (int m = 0; m < 2; ++m) {
                    const int mt = (m == 0) ? mt0 : mt1;
#pragma unroll
                    for (int r = 0; r < 4; ++r) {
                        const int row = mt * 16 + kq * 4 + r;
                        const float* mrow = &mhs[row * 12 + 3 * jj];
                        const float z    = sigmoidf_(vals[m][r] + mrow[0]);
                        const float rg   = sigmoidf_(v1[m][r] + mrow[1]);
                        const float cand = tanhf(v2[m][r] + rg * mrow[2]);
                        const float hn = z * hreg[m][r] + (1.0f - z) * cand;
                        hreg[m][r] = hn;
                        const int fi = frag_idx(row, j);
                        _Float16 hi, lo;
                        split16(hn, &hi, &lo);
                        st_h16(&hH[fi], hi);
                        st_h16(&hL[fi], lo);
                    }
                }
            }
            gbar(bar, ++gen, isdes);
        }
    }
}

// ===========================================================================
// Fallback path (round-2 kernels) — used only if cooperative launch fails.
// ===========================================================================
__global__ __launch_bounds__(128) void gemmA(
    const float* __restrict__ A,
    const float* __restrict__ W0, const float* __restrict__ b0, int act0,
    float* __restrict__ C0, float* __restrict__ C2,
    const float* __restrict__ W1, const float* __restrict__ b1,
    float* __restrict__ C1)
{
    __shared__ __align__(16) float Ass[32][36];
    __shared__ __align__(16) float Ws[32][68];
    const int tid = threadIdx.x;
    const int bx = blockIdx.x, by = blockIdx.y;
    const int r0 = by * 32;
    const bool reg0 = (bx < 16);
    const int c0 = reg0 ? bx * 64 : (bx - 16) * 64;
    const float* __restrict__ W = reg0 ? W0 : W1;
    const int ldw = reg0 ? 1024 : 3072;
    const int arow = tid >> 2;
    const int ak   = (tid & 3) << 2;
    const int wrow = tid >> 4;
    const int wcol = (tid & 15) << 2;
    const int ty = tid >> 4;
    const int tx = tid & 15;
    float acc[4][4] = {};
    const float* Ap = A + (size_t)(r0 + arow) * 1024 + ak;
    const float* Wp = W + (size_t)wrow * ldw + c0 + wcol;
    for (int k0 = 0; k0 < 1024; k0 += 32) {
        const float4 a0 = *(const float4*)(Ap + k0);
        const float4 a1 = *(const float4*)(Ap + k0 + 16);
        const float4 w0 = *(const float4*)(Wp + (size_t)k0 * ldw);
        const float4 w1 = *(const float4*)(Wp + (size_t)(k0 + 8) * ldw);
        const float4 w2 = *(const float4*)(Wp + (size_t)(k0 + 16) * ldw);
        const float4 w3 = *(const float4*)(Wp + (size_t)(k0 + 24) * ldw);
        __syncthreads();
        Ass[ak + 0][arow] = a0.x; Ass[ak + 1][arow] = a0.y;
        Ass[ak + 2][arow] = a0.z; Ass[ak + 3][arow] = a0.w;
        Ass[ak + 16][arow] = a1.x; Ass[ak + 17][arow] = a1.y;
        Ass[ak + 18][arow] = a1.z; Ass[ak + 19][arow] = a1.w;
        *(float4*)&Ws[wrow][wcol]      = w0;
        *(float4*)&Ws[wrow + 8][wcol]  = w1;
        *(float4*)&Ws[wrow + 16][wcol] = w2;
        *(float4*)&Ws[wrow + 24][wcol] = w3;
        __syncthreads();
#pragma unroll
        for (int kk = 0; kk < 32; ++kk) {
            const float4 a4 = *(const float4*)&Ass[kk][ty << 2];
            const float4 w4 = *(const float4*)&Ws[kk][tx << 2];
            const float a[4] = {a4.x, a4.y, a4.z, a4.w};
            const float w[4] = {w4.x, w4.y, w4.z, w4.w};
#pragma unroll
            for (int i = 0; i < 4; ++i)
#pragma unroll
                for (int j = 0; j < 4; ++j)
                    acc[i][j] = fmaf(a[i], w[j], acc[i][j]);
        }
    }
    const float* bias = reg0 ? b0 : b1;
    const float4 bv = *(const float4*)(bias + c0 + (tx << 2));
    const float bb[4] = {bv.x, bv.y, bv.z, bv.w};
#pragma unroll
    for (int i = 0; i < 4; ++i) {
        const int row = r0 + (ty << 2) + i;
        float v[4];
#pragma unroll
        for (int j = 0; j < 4; ++j) {
            float tv = acc[i][j] + bb[j];
            if (reg0) { tv = (act0 == 1) ? fmaxf(tv, 0.0f) : tanhf(tv); }
            v[j] = tv;
        }
        const float4 o = make_float4(v[0], v[1], v[2], v[3]);
        if (reg0) {
            *(float4*)(C0 + (size_t)row * 1024 + c0 + (tx << 2)) = o;
            if (C2)
                *(float4*)(C2 + (size_t)row * (TSTEPS * HDIM) + c0 + (tx << 2)) = o;
        } else {
            *(float4*)(C1 + (size_t)row * TH3 + c0 + (tx << 2)) = o;
        }
    }
}

__global__ __launch_bounds__(128) void gemmB(
    const float* __restrict__ A,
    const float* __restrict__ Wk,
    const float* __restrict__ bg,
    const float* __restrict__ mh,
    float* __restrict__ h)
{
    __shared__ __align__(16) float Ass[32][36];
    __shared__ __align__(16) float Ws[3][32][20];
    const int tid = threadIdx.x;
    const int j0 = blockIdx.x * 16;
    const int r0 = blockIdx.y * 32;
    const int arow = tid >> 2;
    const int ak   = (tid & 3) << 2;
    const int wr   = tid >> 2;
    const int wc   = (tid & 3) << 2;
    const int ty = tid >> 4;
    const int tx = tid & 15;
    float acc[3][4] = {};
    const float* Ap = A + (size_t)(r0 + arow) * 1024 + ak;
    const float* Wp = Wk + (size_t)wr * TH3 + j0 + wc;
    for (int k0 = 0; k0 < 1024; k0 += 32) {
        const float4 a0 = *(const float4*)(Ap + k0);
        const float4 a1 = *(const float4*)(Ap + k0 + 16);
        float4 wv[3];
#pragma unroll
        for (int c = 0; c < 3; ++c)
            wv[c] = *(const float4*)(Wp + (size_t)k0 * TH3 + c * 1024);
        __syncthreads();
        Ass[ak + 0][arow] = a0.x; Ass[ak + 1][arow] = a0.y;
        Ass[ak + 2][arow] = a0.z; Ass[ak + 3][arow] = a0.w;
        Ass[ak + 16][arow] = a1.x; Ass[ak + 17][arow] = a1.y;
        Ass[ak + 18][arow] = a1.z; Ass[ak + 19][arow] = a1.w;
#pragma unroll
        for (int c = 0; c < 3; ++c)
            *(float4*)&Ws[c][wr][wc] = wv[c];
        __syncthreads();
#pragma unroll
        for (int kk = 0; kk < 32; ++kk) {
            const float4 a4 = *(const float4*)&Ass[kk][ty << 2];
            const float a[4] = {a4.x, a4.y, a4.z, a4.w};
            const float wz = Ws[0][kk][tx];
            const float wr_ = Ws[1][kk][tx];
            const float wh = Ws[2][kk][tx];
#pragma unroll
            for (int i = 0; i < 4; ++i) {
                acc[0][i] = fmaf(a[i], wz, acc[0][i]);
                acc[1][i] = fmaf(a[i], wr_, acc[1][i]);
                acc[2][i] = fmaf(a[i], wh, acc[2][i]);
            }
        }
    }
    const int j = j0 + tx;
    const float bz = bg[j];
    const float br = bg[HDIM + j];
    const float bh = bg[2 * HDIM + j];
#pragma unroll
    for (int i = 0; i < 4; ++i) {
        const int row = r0 + (ty << 2) + i;
        const float* mhp = mh + (size_t)row * TH3;
        const float z  = sigmoidf_(acc[0][i] + bz + mhp[j]);
        const float rg = sigmoidf_(acc[1][i] + br + mhp[HDIM + j]);
        const float cand = tanhf(acc[2][i] + bh + rg * mhp[2 * HDIM + j]);
        const size_t hi = (size_t)row * HDIM + j;
        const float ho = h[hi];
        h[hi] = z * ho + (1.0f - z) * cand;
    }
}

extern "C" void kernel_launch(void* const* d_in, const int* in_sizes, int n_in,
                              void* d_out, int out_size, void* d_ws, size_t ws_size,
                              hipStream_t stream) {
    const float* x     = (const float*)d_in[0];
    const float* W_fs  = (const float*)d_in[1];
    const float* b_fs  = (const float*)d_in[2];
    const float* W_out = (const float*)d_in[3];
    const float* b_out = (const float*)d_in[4];
    const float* W_k   = (const float*)d_in[5];
    const float* W_r   = (const float*)d_in[6];
    const float* b_gru = (const float*)d_in[7];
    float* out = (float*)d_out;            // [B, T, H]

    char* ws = (char*)d_ws;
    _Float16* hH = (_Float16*)(ws);                  // 512KB each plane
    _Float16* hL = (_Float16*)(ws + 512 * 1024);
    _Float16* oH = (_Float16*)(ws + 1024 * 1024);
    _Float16* oL = (_Float16*)(ws + 1536 * 1024);
    unsigned* bar = (unsigned*)(ws + 2048 * 1024);   // barrier + election (2KB)

    // barrier counters must start at 0 every launch (graph-capture safe)
    hipMemsetAsync(bar, 0, 2048, stream);

    void* args[] = {
        (void*)&x, (void*)&W_fs, (void*)&b_fs, (void*)&W_out, (void*)&b_out,
        (void*)&W_k, (void*)&W_r, (void*)&b_gru, (void*)&out,
        (void*)&hH, (void*)&hL, (void*)&oH, (void*)&oL, (void*)&bar
    };
    const size_t lds_bytes = 131072 + 12288;         // panels 128KB + mhs 12KB
    hipError_t err = hipLaunchCooperativeKernel(
        (const void*)decoder_mfma, dim3(256), dim3(512),
        args, lds_bytes, stream);

    if (err != hipSuccess) {
        // fallback: round-2 multi-launch fp32 path
        float* h    = (float*)d_ws;
        float* outb = h    + BROWS * HDIM;
        float* mhf  = outb + BROWS * HDIM;
        const dim3 blk(128);
        const dim3 gridInit(16, 8);
        const dim3 gridA(64, 8);
        const dim3 gridB(64, 8);
        gemmA<<<gridInit, blk, 0, stream>>>(x, W_fs, b_fs, 2, h, nullptr,
                                            nullptr, nullptr, nullptr);
        for (int t = 0; t < TSTEPS; ++t) {
            float* c2 = (t >= 1) ? (out + (size_t)(t - 1) * HDIM) : nullptr;
            gemmA<<<gridA, blk, 0, stream>>>(h, W_out, b_out, 1, outb, c2,
                                             W_r, b_gru + TH3, mhf);
            gemmB<<<gridB, blk, 0, stream>>>(outb, W_k, b_gru, mhf, h);
        }
        gemmA<<<gridInit, blk, 0, stream>>>(h, W_out, b_out, 1, outb,
                                            out + (size_t)(TSTEPS - 1) * HDIM,
                                            nullptr, nullptr, nullptr);
    }
}